// Round 9
// baseline (226.621 us; speedup 1.0000x reference)
//
#include <hip/hip_runtime.h>
#include <hip/hip_bf16.h>

typedef __hip_bfloat16 bf16;
typedef __bf16 bf16x8 __attribute__((ext_vector_type(8)));
typedef float f32x4 __attribute__((ext_vector_type(4)));

#define BB 4
#define HH 240
#define WW 320
#define CG 64
#define NCO 24
#define HWSZ (HH*WW)

__device__ __forceinline__ float ldF(const void* __restrict__ p, long i, int isbf) {
    if (isbf) return __bfloat162float(((const bf16*)p)[i]);
    return ((const float*)p)[i];
}

__device__ __forceinline__ int detect_bf16(const void* asc) {
    // aff_scale_const == 4.0f: fp32 LE low u16 = 0x0000, bf16 = 0x4080.
    return ((const unsigned short*)asc)[0] != 0;
}

__device__ __forceinline__ unsigned short f2bfbits(float v) {
    bf16 h = __float2bfloat16(v);
    return *(unsigned short*)&h;
}

// load 4 consecutive elements as bf16 bits (fp32 path converts; bf16 path copies)
__device__ __forceinline__ void ld4bf(const void* __restrict__ p, long i, int isbf,
                                      unsigned short* __restrict__ o) {
    if (isbf) {
        ushort4 v = *(const ushort4*)((const unsigned short*)p + i);
        o[0] = v.x; o[1] = v.y; o[2] = v.z; o[3] = v.w;
    } else {
        float4 v = *(const float4*)((const float*)p + i);
        o[0] = f2bfbits(v.x); o[1] = f2bfbits(v.y);
        o[2] = f2bfbits(v.z); o[3] = f2bfbits(v.w);
    }
}

// ---------------------------------------------------------------------------
// Kernel 1 (old, channel-major) : emergency fallback path only
// ---------------------------------------------------------------------------
__global__ __launch_bounds__(256) void upsample_kernel(const void* __restrict__ tin,
                                                       const void* __restrict__ asc,
                                                       float* __restrict__ fea) {
    int isbf = detect_bf16(asc);
    int idx = blockIdx.x * 256 + threadIdx.x;
    if (idx >= BB * 8 * HWSZ) return;
    int j = idx % WW;
    int rest = idx / WW;
    int i = rest % HH;
    int bc = rest / HH;
    float sy = 0.5f * (float)i - 0.25f;
    float sx = 0.5f * (float)j - 0.25f;
    float y0f = floorf(sy), x0f = floorf(sx);
    float wy = sy - y0f, wx = sx - x0f;
    int y0 = (int)y0f, x0 = (int)x0f;
    int y0c = min(max(y0, 0), 119), y1c = min(max(y0 + 1, 0), 119);
    int x0c = min(max(x0, 0), 159), x1c = min(max(x0 + 1, 0), 159);
    long base = (long)bc * 120 * 160;
    float v00 = ldF(tin, base + y0c * 160 + x0c, isbf);
    float v01 = ldF(tin, base + y0c * 160 + x1c, isbf);
    float v10 = ldF(tin, base + y1c * 160 + x0c, isbf);
    float v11 = ldF(tin, base + y1c * 160 + x1c, isbf);
    fea[idx] = (1.f - wy) * ((1.f - wx) * v00 + wx * v01)
             + wy * ((1.f - wx) * v10 + wx * v11);
}

// ---------------------------------------------------------------------------
// Kernel 0: tiny NCHW -> NHWC transpose of tgtimg_fea (2.4 MB; coalesced read)
// ---------------------------------------------------------------------------
__global__ __launch_bounds__(256) void tgt_cl_kernel(const void* __restrict__ tin,
                                                     const void* __restrict__ asc,
                                                     float* __restrict__ tcl) {
    int isbf = detect_bf16(asc);
    int idx = blockIdx.x * 256 + threadIdx.x;
    if (idx >= BB * 8 * 120 * 160) return;
    int x = idx % 160;
    int r = idx / 160;
    int yy = r % 120;
    int rc = r / 120;
    int ch = rc % 8;
    int b = rc / 8;
    float v = ldF(tin, idx, isbf);
    tcl[((((size_t)b * 120 + yy) * 160 + x) << 3) + ch] = v;
}

// ---------------------------------------------------------------------------
// Kernel 1b: upsample from channels-last source -> channels-last dest.
// ---------------------------------------------------------------------------
__global__ __launch_bounds__(256) void upsample_cl2_kernel(const float* __restrict__ tcl,
                                                           float* __restrict__ fea_cl) {
    int idx = blockIdx.x * 256 + threadIdx.x;
    if (idx >= BB * HWSZ) return;
    int j = idx % WW;
    int rest = idx / WW;
    int i = rest % HH;
    int b = rest / HH;
    float sy = 0.5f * (float)i - 0.25f;
    float sx = 0.5f * (float)j - 0.25f;
    float y0f = floorf(sy), x0f = floorf(sx);
    float wy = sy - y0f, wx = sx - x0f;
    int y0 = (int)y0f, x0 = (int)x0f;
    int y0c = min(max(y0, 0), 119), y1c = min(max(y0 + 1, 0), 119);
    int x0c = min(max(x0, 0), 159), x1c = min(max(x0 + 1, 0), 159);

    const float* s = tcl + ((size_t)b * 120 * 160) * 8;
    const float* p00 = s + ((size_t)y0c * 160 + x0c) * 8;
    const float* p01 = s + ((size_t)y0c * 160 + x1c) * 8;
    const float* p10 = s + ((size_t)y1c * 160 + x0c) * 8;
    const float* p11 = s + ((size_t)y1c * 160 + x1c) * 8;
    float v00[8], v01[8], v10[8], v11[8], o[8];
    *(float4*)&v00[0] = *(const float4*)p00; *(float4*)&v00[4] = *(const float4*)(p00 + 4);
    *(float4*)&v01[0] = *(const float4*)p01; *(float4*)&v01[4] = *(const float4*)(p01 + 4);
    *(float4*)&v10[0] = *(const float4*)p10; *(float4*)&v10[4] = *(const float4*)(p10 + 4);
    *(float4*)&v11[0] = *(const float4*)p11; *(float4*)&v11[4] = *(const float4*)(p11 + 4);
#pragma unroll
    for (int ch = 0; ch < 8; ch++)
        o[ch] = (1.f - wy) * ((1.f - wx) * v00[ch] + wx * v01[ch])
              + wy * ((1.f - wx) * v10[ch] + wx * v11[ch]);
    float* dst = fea_cl + (size_t)idx * 8;
    *(float4*)dst = make_float4(o[0], o[1], o[2], o[3]);
    *(float4*)(dst + 4) = make_float4(o[4], o[5], o[6], o[7]);
}

// ---------------------------------------------------------------------------
// Prep A (R6): guidance NCHW -> channels-last bf16 gT[b][y][x][ci], vectorized.
// ---------------------------------------------------------------------------
__global__ __launch_bounds__(256) void prep_guidance2(const void* __restrict__ g,
                                                      const void* __restrict__ asc,
                                                      unsigned short* __restrict__ gTu) {
    int isbf = detect_bf16(asc);
    const int x0 = blockIdx.x * 64;
    const int y  = blockIdx.y;
    const int b  = blockIdx.z;
    __shared__ unsigned int sh2[64][33];
    const int t = threadIdx.x;

#pragma unroll
    for (int it = 0; it < 2; it++) {
        int cp = it * 16 + (t >> 4);   // channel pair 0..31
        int xq = t & 15;               // 4-px group 0..15
        long base0 = ((long)(b * CG + 2 * cp) * HH + y) * WW + x0 + 4 * xq;
        long base1 = base0 + (long)HH * WW;
        unsigned short lo[4], hi[4];
        ld4bf(g, base0, isbf, lo);
        ld4bf(g, base1, isbf, hi);
#pragma unroll
        for (int k = 0; k < 4; k++)
            sh2[4 * xq + k][cp] = (unsigned int)lo[k] | ((unsigned int)hi[k] << 16);
    }
    __syncthreads();

#pragma unroll
    for (int it = 0; it < 2; it++) {
        int s = it * 256 + t;
        int xg = s >> 3;      // pixel 0..63
        int cb = s & 7;       // 8-channel block 0..7
        int4 v = make_int4((int)sh2[xg][cb * 4 + 0], (int)sh2[xg][cb * 4 + 1],
                           (int)sh2[xg][cb * 4 + 2], (int)sh2[xg][cb * 4 + 3]);
        *(int4*)&gTu[((((long)b * HH + y) * WW + x0 + xg) << 6) + cb * 8] = v;
    }
}

// ---------------------------------------------------------------------------
// Prep B: weights -> MFMA B-fragment layout Bp[t][n(32, 24 real)][k'(32)] bf16
// ---------------------------------------------------------------------------
__global__ __launch_bounds__(256) void prep_weights(const void* __restrict__ w,
                                                    const void* __restrict__ asc,
                                                    unsigned short* __restrict__ Bpu) {
    int isbf = detect_bf16(asc);
    int idx = blockIdx.x * 256 + threadIdx.x;
    if (idx >= 18 * 32 * 32) return;
    int t = idx >> 10;
    int r = idx & 1023;
    int n = r >> 5;
    int k = r & 31;
    int tap = t >> 1;
    int ch = t & 1;
    float v = 0.f;
    if (n < NCO)
        v = ldF(w, ((long)n * CG + ch * 32 + k) * 9 + tap, isbf);
    Bpu[idx] = f2bfbits(v);
}

// ---------------------------------------------------------------------------
// Kernel 2 (R9): LDS-staged MFMA conv + offset planes + fused cos; 2 rows/block.
//
// R8 post-mortem: 61.7us, Occupancy 22% < the 37.5% its 3-blocks/CU LDS cap
// allows — only 1200 blocks (4.7/CU, ragged 2-wave schedule) and 4 serial cos
// rows x 8 barriers per block. R9: 2 output rows/block (grid 5x120x4 = 2400
// blocks). LDS 33.8KB (shA 4 halo rows; shO[2][16][67]+S fit inside) -> 4
// blocks/CU = 50% occupancy cap, 2x blocks for balance, half the serial cos
// tail. Staging halo cost: 2 rows-read per row-computed (FETCH ~44MB, +1.2us
// BW — cheap vs the latency win). FP expressions/order unchanged.
// ---------------------------------------------------------------------------
__global__ __launch_bounds__(256, 4) void conv_mfma4_kernel(const unsigned short* __restrict__ gTu,
                                                            const unsigned short* __restrict__ Bpu,
                                                            const void* __restrict__ bias,
                                                            const void* __restrict__ asc,
                                                            const float* __restrict__ fea_cl,
                                                            float* __restrict__ oa,
                                                            float* __restrict__ cosb,
                                                            float* __restrict__ out) {
    int isbf = detect_bf16(asc);
    const int x0 = blockIdx.x * 64;
    const int y0 = blockIdx.y * 2;
    const int b  = blockIdx.z;
    const int tid = threadIdx.x;
    const int bx = blockIdx.x;

    __shared__ unsigned short shA[4 * 66 * 64];   // 33792 B union:
    float* shO = (float*)shA;                     //   [2][16][67] f32 = 8576 B
    float* S   = (float*)((char*)shA + 8704);     //   [64][65] f32  = 16640 B

    // ---- stage rows y0-1..y0+2, px x0-1..x0+64, 64 ch bf16 (33792 B) ----
#pragma unroll
    for (int it = 0; it < 9; it++) {
        int s = it * 256 + tid;
        if (s < 2112) {
            int row = s / 528;          // 528 = 66 px * 8 blocks
            int rem = s - row * 528;
            int xi = rem >> 3;
            int blk = rem & 7;
            int y = y0 - 1 + row;
            int x = x0 - 1 + xi;
            int4 v = make_int4(0, 0, 0, 0);
            if (y >= 0 && y < HH && x >= 0 && x < WW)
                v = *(const int4*)(gTu + ((((size_t)b * HH + y) * WW + x) << 6)
                                       + ((blk ^ (xi & 7)) << 3));
            *(int4*)&shA[((row * 66 + xi) << 6) + (blk << 3)] = v;
        }
    }
    __syncthreads();

    const int wid  = tid >> 6;
    const int lane = tid & 63;
    const int m = lane & 15, quad = lane >> 4;

    f32x4 acc0[2], acc1[2];
#pragma unroll
    for (int r = 0; r < 2; r++) {
        acc0[r] = (f32x4){0.f, 0.f, 0.f, 0.f};
        acc1[r] = (f32x4){0.f, 0.f, 0.f, 0.f};
    }

#pragma unroll
    for (int tap = 0; tap < 9; tap++) {
        const int dy = tap / 3, dx = tap % 3;
        const int xi = wid * 16 + m + dx;
#pragma unroll
        for (int h = 0; h < 2; h++) {
            const int t = tap * 2 + h;
            int4 b0i = *(const int4*)(Bpu + ((t * 32 + m) * 32 + quad * 8));
            int4 b1i = *(const int4*)(Bpu + ((t * 32 + 16 + m) * 32 + quad * 8));
            bf16x8 bf0 = __builtin_bit_cast(bf16x8, b0i);
            bf16x8 bf1 = __builtin_bit_cast(bf16x8, b1i);
            const int sw = (((h * 4 + quad) ^ (xi & 7)) << 3);
#pragma unroll
            for (int r = 0; r < 2; r++) {
                int row = r + dy;
                int4 ai = *(const int4*)&shA[(((row * 66 + xi) << 6)) + sw];
                bf16x8 af = __builtin_bit_cast(bf16x8, ai);
                acc0[r] = __builtin_amdgcn_mfma_f32_16x16x32_bf16(af, bf0, acc0[r], 0, 0, 0);
                acc1[r] = __builtin_amdgcn_mfma_f32_16x16x32_bf16(af, bf1, acc1[r], 0, 0, 0);
            }
        }
    }

    const int n = m;
    const int x0w = x0 + wid * 16;
    float bias0 = ldF(bias, n, isbf);
    float bias1 = (n < 8) ? ldF(bias, 16 + n, isbf) : 0.f;

    // ---- oa write (all 24 ch) + stage acc0 into shO ----
    __syncthreads();                    // shA reads done; reuse as shO/S
#pragma unroll
    for (int r = 0; r < 2; r++) {
        int yy = y0 + r;
#pragma unroll
        for (int rr = 0; rr < 4; rr++) {
            int px = x0w + quad * 4 + rr;
            float v0 = acc0[r][rr] + bias0;
            float* dst = &oa[(((size_t)b * HH + yy) * WW + px) * NCO];
            dst[n] = v0;
            shO[(r * 16 + n) * 67 + (px - x0)] = v0;
            if (n < 8) dst[16 + n] = acc1[r][rr] + bias1;
        }
    }
    __syncthreads();

    // ---- 16 offset planes, coalesced (reads shO): 2048 floats ----
#pragma unroll
    for (int it = 0; it < 8; it++) {
        int s = it * 256 + tid;
        int px = s & 63;
        int rest = s >> 6;
        int nn = rest & 15;
        int r = rest >> 4;
        int och = (nn < 8) ? nn : nn + 2;
        out[(((size_t)b * 18 + och) * HH + (y0 + r)) * WW + x0 + px]
            = shO[(r * 16 + nn) * 67 + px];
    }

    // ---- fused cos: per source row r, phase1 gather -> S, then reduce ----
    const float* feaB = fea_cl + (size_t)b * HWSZ * 8;
#pragma unroll 1
    for (int r = 0; r < 2; r++) {
        const int pi = y0 + r;
#pragma unroll
        for (int k = 0; k < 2; k++) {
            int s = k * 256 + tid;
            int c = s >> 6;            // 0..7 (wave-uniform)
            int qj_l = s & 63;
            int qj = x0 + qj_l;
            float ox = shO[(r * 16 + 2 * c) * 67 + qj_l];
            float oy = shO[(r * 16 + 2 * c + 1) * 67 + qj_l];
            float add = (c < 4) ? (float)pi : (float)qj;
            float px = ox + add, py = oy + add;

            float x0f = floorf(px), y0f = floorf(py);
            float wx = px - x0f, wy = py - y0f;
            int xx0 = (int)x0f, yy0 = (int)y0f;
            int x0c = min(max(xx0, 0), WW - 1), x1c = min(max(xx0 + 1, 0), WW - 1);
            int y0c = min(max(yy0, 0), HH - 1), y1c = min(max(yy0 + 1, 0), HH - 1);
            float mx0 = (xx0 == x0c) ? 1.f : 0.f;
            float mx1 = (xx0 + 1 == x1c) ? 1.f : 0.f;
            float my0 = (yy0 == y0c) ? 1.f : 0.f;
            float my1 = (yy0 + 1 == y1c) ? 1.f : 0.f;
            float aw = mx0 * (1.f - wx);
            float bw = mx1 * wx;
            float tw = my0 * (1.f - wy);
            float dw = my1 * wy;

            const float* r0 = feaB + (size_t)y0c * WW * 8;
            const float* r1 = feaB + (size_t)y1c * WW * 8;
            float v00[8], v01[8], v10[8], v11[8];
            *(float4*)&v00[0] = *(const float4*)(r0 + x0c * 8);
            *(float4*)&v00[4] = *(const float4*)(r0 + x0c * 8 + 4);
            *(float4*)&v01[0] = *(const float4*)(r0 + x1c * 8);
            *(float4*)&v01[4] = *(const float4*)(r0 + x1c * 8 + 4);
            *(float4*)&v10[0] = *(const float4*)(r1 + x0c * 8);
            *(float4*)&v10[4] = *(const float4*)(r1 + x0c * 8 + 4);
            *(float4*)&v11[0] = *(const float4*)(r1 + x1c * 8);
            *(float4*)&v11[4] = *(const float4*)(r1 + x1c * 8 + 4);

            int base = qj_l * 65 + c * 8;
#pragma unroll
            for (int ch = 0; ch < 8; ch++)
                S[base + ch] = tw * (aw * v00[ch] + bw * v01[ch])
                             + dw * (aw * v10[ch] + bw * v11[ch]);
        }
        __syncthreads();

        {
            int pix = tid >> 2;     // 0..63: (g, c_img)
            int cp  = tid & 3;      // computes c = 2cp, 2cp+1
            int g = pix >> 3;
            int c_img = pix & 7;
            int i = c_img * 30 + (pi >> 3);
            int j = (pi & 7) * 40 + bx * 8 + g;
            const float* fp = feaB + ((size_t)i * WW + j) * 8;
            float f[8];
            *(float4*)&f[0] = *(const float4*)fp;
            *(float4*)&f[4] = *(const float4*)(fp + 4);
            float a0 = 0.f, a1 = 0.f;
            int c0 = 2 * cp;
#pragma unroll
            for (int nn = 0; nn < 8; nn++) {   // ascending n: same FP order
                float fn = f[nn];
                int rb = (8 * g + nn) * 65 + c_img;
                a0 += fn * S[rb + c0 * 8];
                a1 += fn * S[rb + (c0 + 1) * 8];
            }
            float* dst = cosb + (((size_t)b * HH + i) * WW + j) * 8 + c0;
            *(float2*)dst = make_float2(a0, a1);
        }
        __syncthreads();
    }
}

// ---------------------------------------------------------------------------
// Fallback scalar conv (only if ws too small for gTu).
// ---------------------------------------------------------------------------
__global__ __launch_bounds__(256, 4) void conv_fallback(const void* __restrict__ g,
                                                        const void* __restrict__ w,
                                                        const void* __restrict__ bias,
                                                        const void* __restrict__ asc,
                                                        float* __restrict__ oa) {
    int isbf = detect_bf16(asc);
    const int b = blockIdx.z;
    const int i0 = blockIdx.y * 16;
    const int j0 = blockIdx.x * 16;
    const int tx = threadIdx.x & 15;
    const int ty = threadIdx.x >> 4;

    __shared__ float gl[8][18][20];
    __shared__ float wl[8][NCO][10];

    float acc[NCO];
#pragma unroll
    for (int c = 0; c < NCO; c++) acc[c] = ldF(bias, c, isbf);

    for (int ci0 = 0; ci0 < CG; ci0 += 8) {
        __syncthreads();
        for (int idx = threadIdx.x; idx < 8 * NCO * 9; idx += 256) {
            int t = idx % 9;
            int rest = idx / 9;
            int cc = rest & 7;
            int co = rest >> 3;
            wl[cc][co][t] = ldF(w, (long)(co * CG + ci0 + cc) * 9 + t, isbf);
        }
        for (int idx = threadIdx.x; idx < 8 * 18 * 18; idx += 256) {
            int cc = idx / 324;
            int rem = idx - cc * 324;
            int r = rem / 18;
            int c2 = rem - r * 18;
            int gi = i0 - 1 + r;
            int gj = j0 - 1 + c2;
            float v = 0.f;
            if (gi >= 0 && gi < HH && gj >= 0 && gj < WW)
                v = ldF(g, ((long)(b * CG + ci0 + cc) * HH + gi) * WW + gj, isbf);
            gl[cc][r][c2] = v;
        }
        __syncthreads();
#pragma unroll
        for (int cc = 0; cc < 8; cc++) {
            float ga[9];
#pragma unroll
            for (int dy = 0; dy < 3; dy++)
#pragma unroll
                for (int dx = 0; dx < 3; dx++)
                    ga[dy * 3 + dx] = gl[cc][ty + dy][tx + dx];
#pragma unroll 4
            for (int co = 0; co < NCO; co++) {
                float s = 0.f;
#pragma unroll
                for (int t = 0; t < 9; t++)
                    s += wl[cc][co][t] * ga[t];
                acc[co] += s;
            }
        }
    }
    int i = i0 + ty, j = j0 + tx;
    float4* p = (float4*)&oa[(((size_t)b * HH + i) * WW + j) * NCO];
#pragma unroll
    for (int q = 0; q < 6; q++)
        p[q] = make_float4(acc[4 * q], acc[4 * q + 1], acc[4 * q + 2], acc[4 * q + 3]);
}

// ---------------------------------------------------------------------------
// Branchless bilinear, zero outside: clamp indices, mask corner weights.
// ---------------------------------------------------------------------------
__device__ __forceinline__ float bil_zero_f32(const float* __restrict__ img,
                                              float x, float y) {
    float x0f = floorf(x), y0f = floorf(y);
    float wx = x - x0f, wy = y - y0f;
    int x0 = (int)x0f, y0 = (int)y0f;
    int x0c = min(max(x0, 0), WW - 1), x1c = min(max(x0 + 1, 0), WW - 1);
    int y0c = min(max(y0, 0), HH - 1), y1c = min(max(y0 + 1, 0), HH - 1);
    float mx0 = (x0 == x0c) ? 1.f : 0.f;
    float mx1 = (x0 + 1 == x1c) ? 1.f : 0.f;
    float my0 = (y0 == y0c) ? 1.f : 0.f;
    float my1 = (y0 + 1 == y1c) ? 1.f : 0.f;
    const float* r0 = img + (size_t)y0c * WW;
    const float* r1 = img + (size_t)y1c * WW;
    float v00 = r0[x0c], v01 = r0[x1c], v10 = r1[x0c], v11 = r1[x1c];
    return my0 * (1.f - wy) * (mx0 * (1.f - wx) * v00 + mx1 * wx * v01)
         + my1 * wy * (mx0 * (1.f - wx) * v10 + mx1 * wx * v11);
}

__device__ __forceinline__ float bil_zero_poly(const void* __restrict__ img, long base,
                                               float x, float y, int isbf) {
    float x0f = floorf(x), y0f = floorf(y);
    float wx = x - x0f, wy = y - y0f;
    int x0 = (int)x0f, y0 = (int)y0f;
    int x0c = min(max(x0, 0), WW - 1), x1c = min(max(x0 + 1, 0), WW - 1);
    int y0c = min(max(y0, 0), HH - 1), y1c = min(max(y0 + 1, 0), HH - 1);
    float mx0 = (x0 == x0c) ? 1.f : 0.f;
    float mx1 = (x0 + 1 == x1c) ? 1.f : 0.f;
    float my0 = (y0 == y0c) ? 1.f : 0.f;
    float my1 = (y0 + 1 == y1c) ? 1.f : 0.f;
    long r0 = base + (long)y0c * WW;
    long r1 = base + (long)y1c * WW;
    float v00 = ldF(img, r0 + x0c, isbf), v01 = ldF(img, r0 + x1c, isbf);
    float v10 = ldF(img, r1 + x0c, isbf), v11 = ldF(img, r1 + x1c, isbf);
    return my0 * (1.f - wy) * (mx0 * (1.f - wx) * v00 + mx1 * wx * v01)
         + my1 * wy * (mx0 * (1.f - wx) * v10 + mx1 * wx * v11);
}

// ---------------------------------------------------------------------------
// Kernel 3a (mid path only): source-centric cosine affinity.
// ---------------------------------------------------------------------------
__global__ __launch_bounds__(256, 4) void cos_kernel(const float* __restrict__ oa,
                                                     const float* __restrict__ fea_cl,
                                                     float* __restrict__ cos_buf) {
    __shared__ float S_lds[64 * 65];
    const int bx = blockIdx.x;   // 0..4 (qj chunk of 64)
    const int pi = blockIdx.y;   // 0..239
    const int b  = blockIdx.z;
    const int tid = threadIdx.x;
    const int qj_l = tid & 63;
    const int cpair = tid >> 6;  // 0..3 -> c in {2cp, 2cp+1}
    const int qj = bx * 64 + qj_l;

    const float* feaB = fea_cl + (size_t)b * HWSZ * 8;
    const float4 ov = *(const float4*)&oa[(((size_t)b * HH + pi) * WW + qj) * NCO + 4 * cpair];

#pragma unroll
    for (int t = 0; t < 2; t++) {
        int c = 2 * cpair + t;
        float ox = (t == 0) ? ov.x : ov.z;
        float oy = (t == 0) ? ov.y : ov.w;
        float add = (c < 4) ? (float)pi : (float)qj;   // wave-uniform branch
        float px = ox + add, py = oy + add;

        float x0f = floorf(px), y0f = floorf(py);
        float wx = px - x0f, wy = py - y0f;
        int x0 = (int)x0f, y0 = (int)y0f;
        int x0c = min(max(x0, 0), WW - 1), x1c = min(max(x0 + 1, 0), WW - 1);
        int y0c = min(max(y0, 0), HH - 1), y1c = min(max(y0 + 1, 0), HH - 1);
        float mx0 = (x0 == x0c) ? 1.f : 0.f;
        float mx1 = (x0 + 1 == x1c) ? 1.f : 0.f;
        float my0 = (y0 == y0c) ? 1.f : 0.f;
        float my1 = (y0 + 1 == y1c) ? 1.f : 0.f;
        float aw = mx0 * (1.f - wx);
        float bw = mx1 * wx;
        float tw = my0 * (1.f - wy);
        float dw = my1 * wy;

        const float* r0 = feaB + (size_t)y0c * WW * 8;
        const float* r1 = feaB + (size_t)y1c * WW * 8;
        float v00[8], v01[8], v10[8], v11[8];
        *(float4*)&v00[0] = *(const float4*)(r0 + x0c * 8);
        *(float4*)&v00[4] = *(const float4*)(r0 + x0c * 8 + 4);
        *(float4*)&v01[0] = *(const float4*)(r0 + x1c * 8);
        *(float4*)&v01[4] = *(const float4*)(r0 + x1c * 8 + 4);
        *(float4*)&v10[0] = *(const float4*)(r1 + x0c * 8);
        *(float4*)&v10[4] = *(const float4*)(r1 + x0c * 8 + 4);
        *(float4*)&v11[0] = *(const float4*)(r1 + x1c * 8);
        *(float4*)&v11[4] = *(const float4*)(r1 + x1c * 8 + 4);

        int base = qj_l * 65 + c * 8;
#pragma unroll
        for (int ch = 0; ch < 8; ch++)
            S_lds[base + ch] = tw * (aw * v00[ch] + bw * v01[ch])
                             + dw * (aw * v10[ch] + bw * v11[ch]);
    }

    __syncthreads();

    {
        int pix = tid >> 2;     // 0..63: (g, c_img)
        int cp  = tid & 3;      // computes c = 2cp, 2cp+1
        int g = pix >> 3;
        int c_img = pix & 7;
        int i = c_img * 30 + (pi >> 3);
        int j = (pi & 7) * 40 + bx * 8 + g;
        const float* fp = feaB + ((size_t)i * WW + j) * 8;
        float f[8];
        *(float4*)&f[0] = *(const float4*)fp;
        *(float4*)&f[4] = *(const float4*)(fp + 4);
        float a0 = 0.f, a1 = 0.f;
        int c0 = 2 * cp;
#pragma unroll
        for (int n = 0; n < 8; n++) {       // ascending n: same FP order
            float fn = f[n];
            int rb = (8 * g + n) * 65 + c_img;
            a0 += fn * S_lds[rb + c0 * 8];
            a1 += fn * S_lds[rb + (c0 + 1) * 8];
        }
        float* dst = cos_buf + (((size_t)b * HH + i) * WW + j) * 8 + c0;
        *(float2*)dst = make_float2(a0, a1);
    }
}

// ---------------------------------------------------------------------------
// Kernel 3b (R8, full path): epilogue without offset planes; fast tanh.
// tanh(v) = 1 - 2/(exp(2v)+1): exact at saturation, no NaN, err ~1e-7.
// ---------------------------------------------------------------------------
__global__ __launch_bounds__(256, 4) void final3_kernel(const float* __restrict__ oa,
                                                        const float* __restrict__ cos_buf,
                                                        const void* __restrict__ conf_in,
                                                        const void* __restrict__ asc_p,
                                                        float* __restrict__ out) {
    int isbf = detect_bf16(asc_p);
    int idx = blockIdx.x * 256 + threadIdx.x;
    if (idx >= BB * HWSZ) return;
    int j = idx % WW;
    int rest = idx / WW;
    int i = rest % HH;
    int b = rest / HH;

    float cos_acc[8];
    {
        const float* cp = cos_buf + (size_t)idx * 8;
        float4 ca = *(const float4*)cp;
        float4 cb = *(const float4*)(cp + 4);
        cos_acc[0] = ca.x; cos_acc[1] = ca.y; cos_acc[2] = ca.z; cos_acc[3] = ca.w;
        cos_acc[4] = cb.x; cos_acc[5] = cb.y; cos_acc[6] = cb.z; cos_acc[7] = cb.w;
    }

    const float4* op = (const float4*)&oa[(((size_t)b * HH + i) * WW + j) * NCO];
    float own[24];
#pragma unroll
    for (int q = 0; q < 6; q++) {
        float4 v = op[q];
        own[4 * q] = v.x; own[4 * q + 1] = v.y; own[4 * q + 2] = v.z; own[4 * q + 3] = v.w;
    }

    float asc = ldF(asc_p, 0, isbf) + 1e-8f;
    long cbase = (long)b * HWSZ;

    float a[8];
    float ssum = 0.f;
#pragma unroll
    for (int c = 0; c < 8; c++) {
        float v = own[16 + c] * cos_acc[c];
        float e2 = __expf(2.f * v);
        v = (1.f - 2.f / (e2 + 1.f)) / asc;
        float py2 = own[2 * c] + (float)i;
        float px2 = own[2 * c + 1] + (float)j;
        float cf = bil_zero_poly(conf_in, cbase, px2, py2, isbf);
        v *= cf;
        a[c] = v;
        ssum += fabsf(v);
    }
    ssum += 1e-4f;
    ssum = fmaxf(ssum, 1.0f);
    float inv = 1.0f / ssum;
    float asum = 0.f;
#pragma unroll
    for (int c = 0; c < 8; c++) { a[c] *= inv; asum += a[c]; }
    float aref = 1.0f - asum;

    float vals[9];
#pragma unroll
    for (int c = 0; c < 4; c++) vals[c] = a[c];
    vals[4] = aref;
#pragma unroll
    for (int c = 4; c < 8; c++) vals[c + 1] = a[c];
    float m = vals[0];
#pragma unroll
    for (int k = 1; k < 9; k++) m = fmaxf(m, vals[k]);
    float es = 0.f;
#pragma unroll
    for (int k = 0; k < 9; k++) { vals[k] = __expf(vals[k] - m); es += vals[k]; }
    float ei = 1.0f / es;

    size_t pix = (size_t)i * WW + j;
    size_t base_o = (size_t)b * 18 * HWSZ + pix;
    out[base_o + (size_t)8 * HWSZ] = 0.f;     // zref planes
    out[base_o + (size_t)9 * HWSZ] = 0.f;
    float* aff_out = out + (size_t)BB * 18 * HWSZ;
    size_t base_a = (size_t)b * 9 * HWSZ + pix;
#pragma unroll
    for (int k = 0; k < 9; k++)
        aff_out[base_a + (size_t)k * HWSZ] = vals[k] * ei;
}

// ---------------------------------------------------------------------------
// Kernel 3b (mid path): full epilogue incl. all 18 offset planes.
// ---------------------------------------------------------------------------
__global__ __launch_bounds__(256, 4) void final2_kernel(const float* __restrict__ oa,
                                                        const float* __restrict__ cos_buf,
                                                        const void* __restrict__ conf_in,
                                                        const void* __restrict__ asc_p,
                                                        float* __restrict__ out) {
    int isbf = detect_bf16(asc_p);
    int idx = blockIdx.x * 256 + threadIdx.x;
    if (idx >= BB * HWSZ) return;
    int j = idx % WW;
    int rest = idx / WW;
    int i = rest % HH;
    int b = rest / HH;

    float cos_acc[8];
    {
        const float* cp = cos_buf + (size_t)idx * 8;
        float4 ca = *(const float4*)cp;
        float4 cb = *(const float4*)(cp + 4);
        cos_acc[0] = ca.x; cos_acc[1] = ca.y; cos_acc[2] = ca.z; cos_acc[3] = ca.w;
        cos_acc[4] = cb.x; cos_acc[5] = cb.y; cos_acc[6] = cb.z; cos_acc[7] = cb.w;
    }

    const float4* op = (const float4*)&oa[(((size_t)b * HH + i) * WW + j) * NCO];
    float own[24];
#pragma unroll
    for (int q = 0; q < 6; q++) {
        float4 v = op[q];
        own[4 * q] = v.x; own[4 * q + 1] = v.y; own[4 * q + 2] = v.z; own[4 * q + 3] = v.w;
    }

    float asc = ldF(asc_p, 0, isbf) + 1e-8f;
    long cbase = (long)b * HWSZ;

    float a[8];
    float ssum = 0.f;
#pragma unroll
    for (int c = 0; c < 8; c++) {
        float v = own[16 + c] * cos_acc[c];
        v = tanhf(v) / asc;
        float py2 = own[2 * c] + (float)i;
        float px2 = own[2 * c + 1] + (float)j;
        float cf = bil_zero_poly(conf_in, cbase, px2, py2, isbf);
        v *= cf;
        a[c] = v;
        ssum += fabsf(v);
    }
    ssum += 1e-4f;
    ssum = fmaxf(ssum, 1.0f);
    float inv = 1.0f / ssum;
    float asum = 0.f;
#pragma unroll
    for (int c = 0; c < 8; c++) { a[c] *= inv; asum += a[c]; }
    float aref = 1.0f - asum;

    float vals[9];
#pragma unroll
    for (int c = 0; c < 4; c++) vals[c] = a[c];
    vals[4] = aref;
#pragma unroll
    for (int c = 4; c < 8; c++) vals[c + 1] = a[c];
    float m = vals[0];
#pragma unroll
    for (int k = 1; k < 9; k++) m = fmaxf(m, vals[k]);
    float es = 0.f;
#pragma unroll
    for (int k = 0; k < 9; k++) { vals[k] = __expf(vals[k] - m); es += vals[k]; }
    float ei = 1.0f / es;

    size_t pix = (size_t)i * WW + j;
    size_t base_o = (size_t)b * 18 * HWSZ + pix;
#pragma unroll
    for (int ch = 0; ch < 18; ch++) {
        float v;
        if (ch < 8) v = own[ch];
        else if (ch < 10) v = 0.f;
        else v = own[ch - 2];
        out[base_o + (size_t)ch * HWSZ] = v;
    }
    float* aff_out = out + (size_t)BB * 18 * HWSZ;
    size_t base_a = (size_t)b * 9 * HWSZ + pix;
#pragma unroll
    for (int k = 0; k < 9; k++)
        aff_out[base_a + (size_t)k * HWSZ] = vals[k] * ei;
}

// ---------------------------------------------------------------------------
// OLD monolithic final kernel — emergency fallback only (tiny workspace).
// ---------------------------------------------------------------------------
__global__ __launch_bounds__(256, 4) void final_kernel(const float* __restrict__ oa,
                                                       const float* __restrict__ fea,
                                                       const void* __restrict__ conf_in,
                                                       const void* __restrict__ asc_p,
                                                       float* __restrict__ out) {
    int isbf = detect_bf16(asc_p);
    int idx = blockIdx.x * 256 + threadIdx.x;
    if (idx >= BB * HWSZ) return;
    int j = idx % WW;
    int rest = idx / WW;
    int i = rest % HH;
    int b = rest / HH;

    const float* feaB = fea + (size_t)b * 8 * HWSZ;
    float f[8];
#pragma unroll
    for (int n = 0; n < 8; n++)
        f[n] = feaB[(size_t)n * HWSZ + (size_t)i * WW + j];

    int c_img = i / 30;
    int pi = (i % 30) * 8 + j / 40;
    int pj0 = (j % 40) * 8;
    const float* feaC = feaB + (size_t)c_img * HWSZ;

    float cos_acc[8];
#pragma unroll
    for (int c = 0; c < 8; c++) cos_acc[c] = 0.f;

#pragma unroll 1
    for (int n = 0; n < 8; n++) {
        int qj = pj0 + n;
        const float4* oq = (const float4*)&oa[(((size_t)b * HH + pi) * WW + qj) * NCO];
        float4 o0 = oq[0], o1 = oq[1], o2 = oq[2], o3 = oq[3];
        float off[16] = {o0.x, o0.y, o0.z, o0.w, o1.x, o1.y, o1.z, o1.w,
                         o2.x, o2.y, o2.z, o2.w, o3.x, o3.y, o3.z, o3.w};
        float fn = f[n];
#pragma unroll
        for (int c = 0; c < 8; c++) {
            float add = (c < 4) ? (float)pi : (float)qj;
            float px = off[2 * c] + add;
            float py = off[2 * c + 1] + add;
            cos_acc[c] += fn * bil_zero_f32(feaC, px, py);
        }
    }

    const float4* op = (const float4*)&oa[(((size_t)b * HH + i) * WW + j) * NCO];
    float own[24];
#pragma unroll
    for (int q = 0; q < 6; q++) {
        float4 v = op[q];
        own[4 * q] = v.x; own[4 * q + 1] = v.y; own[4 * q + 2] = v.z; own[4 * q + 3] = v.w;
    }

    float asc = ldF(asc_p, 0, isbf) + 1e-8f;
    long cbase = (long)b * HWSZ;

    float a[8];
    float ssum = 0.f;
#pragma unroll
    for (int c = 0; c < 8; c++) {
        float v = own[16 + c] * cos_acc[c];
        v = tanhf(v) / asc;
        float py2 = own[2 * c] + (float)i;
        float px2 = own[2 * c + 1] + (float)j;
        float cf = bil_zero_poly(conf_in, cbase, px2, py2, isbf);
        v *= cf;
        a[c] = v;
        ssum += fabsf(v);
    }
    ssum += 1e-4f;
    ssum = fmaxf(ssum, 1.0f);
    float inv = 1.0f / ssum;
    float asum = 0.f;
#pragma unroll
    for (int c = 0; c < 8; c++) { a[c] *= inv; asum += a[c]; }
    float aref = 1.0f - asum;

    float vals[9];
#pragma unroll
    for (int c = 0; c < 4; c++) vals[c] = a[c];
    vals[4] = aref;
#pragma unroll
    for (int c = 4; c < 8; c++) vals[c + 1] = a[c];
    float m = vals[0];
#pragma unroll
    for (int k = 1; k < 9; k++) m = fmaxf(m, vals[k]);
    float es = 0.f;
#pragma unroll
    for (int k = 0; k < 9; k++) { vals[k] = __expf(vals[k] - m); es += vals[k]; }
    float ei = 1.0f / es;

    size_t pix = (size_t)i * WW + j;
    size_t base_o = (size_t)b * 18 * HWSZ + pix;
#pragma unroll
    for (int ch = 0; ch < 18; ch++) {
        float v;
        if (ch < 8) v = own[ch];
        else if (ch < 10) v = 0.f;
        else v = own[ch - 2];
        out[base_o + (size_t)ch * HWSZ] = v;
    }
    float* aff_out = out + (size_t)BB * 18 * HWSZ;
    size_t base_a = (size_t)b * 9 * HWSZ + pix;
#pragma unroll
    for (int k = 0; k < 9; k++)
        aff_out[base_a + (size_t)k * HWSZ] = vals[k] * ei;
}

// ---------------------------------------------------------------------------
extern "C" void kernel_launch(void* const* d_in, const int* in_sizes, int n_in,
                              void* d_out, int out_size, void* d_ws, size_t ws_size,
                              hipStream_t stream) {
    const void* guidance = d_in[0];
    const void* gtconf   = d_in[1];
    const void* tgt      = d_in[2];
    const void* conv_w   = d_in[3];
    const void* conv_b   = d_in[4];
    const void* asc      = d_in[5];

    // Workspace layout. gTu (39.3MB) and tcl (2.4MB) time-share "big";
    // cosb has its own region (outlives conv_mfma4 while gTu is live).
    float* oa   = (float*)d_ws;
    float* fea  = oa + (size_t)BB * HWSZ * NCO;
    float* cosb = fea + (size_t)BB * 8 * HWSZ;
    float* big  = cosb + (size_t)BB * 8 * HWSZ;
    unsigned short* gTu = (unsigned short*)big;
    float* tcl  = big;
    unsigned short* Bpu = (unsigned short*)((char*)big + (size_t)39321600);
    const size_t ws_full = (size_t)29491200 + 9830400 + 9830400 + 39321600 + 36864; // 88,510,464
    const size_t ws_mid  = (size_t)29491200 + 9830400 + 9830400;                    // 49,152,000
    float* out = (float*)d_out;

    int n_pix = BB * HWSZ;
    int n_tgt = BB * 8 * 120 * 160;

    if (ws_size >= ws_full) {
        tgt_cl_kernel<<<(n_tgt + 255) / 256, 256, 0, stream>>>(tgt, asc, tcl);
        upsample_cl2_kernel<<<(n_pix + 255) / 256, 256, 0, stream>>>(tcl, fea);
        prep_weights<<<72, 256, 0, stream>>>(conv_w, asc, Bpu);
        dim3 pgrid(WW / 64, HH, BB);
        prep_guidance2<<<pgrid, 256, 0, stream>>>(guidance, asc, gTu);
        dim3 cgrid(WW / 64, HH / 2, BB);
        conv_mfma4_kernel<<<cgrid, 256, 0, stream>>>(gTu, Bpu, conv_b, asc, fea, oa, cosb, out);
        final3_kernel<<<(n_pix + 255) / 256, 256, 0, stream>>>(oa, cosb, gtconf, asc, out);
    } else if (ws_size >= ws_mid) {
        // mid path: no gTu; scalar conv + split cos/final2. tcl aliases cosb
        // (disjoint liveness).
        float* tclm = cosb;
        tgt_cl_kernel<<<(n_tgt + 255) / 256, 256, 0, stream>>>(tgt, asc, tclm);
        upsample_cl2_kernel<<<(n_pix + 255) / 256, 256, 0, stream>>>(tclm, fea);
        dim3 cgrid(WW / 16, HH / 16, BB);
        conv_fallback<<<cgrid, 256, 0, stream>>>(guidance, conv_w, conv_b, asc, oa);
        dim3 ggrid(WW / 64, HH, BB);
        cos_kernel<<<ggrid, 256, 0, stream>>>(oa, fea, cosb);
        final2_kernel<<<(n_pix + 255) / 256, 256, 0, stream>>>(oa, cosb, gtconf, asc, out);
    } else {
        // --- emergency tiny-workspace path (old monolithic) ---
        int n_up = BB * 8 * HWSZ;
        upsample_kernel<<<(n_up + 255) / 256, 256, 0, stream>>>(tgt, asc, fea);
        dim3 cgrid(WW / 16, HH / 16, BB);
        conv_fallback<<<cgrid, 256, 0, stream>>>(guidance, conv_w, conv_b, asc, oa);
        final_kernel<<<(n_pix + 255) / 256, 256, 0, stream>>>(oa, fea, gtconf, asc, out);
    }
}

// Round 10
// 217.261 us; speedup vs baseline: 1.0431x; 1.0431x over previous
//
#include <hip/hip_runtime.h>
#include <hip/hip_bf16.h>

typedef __hip_bfloat16 bf16;
typedef __bf16 bf16x8 __attribute__((ext_vector_type(8)));
typedef float f32x4 __attribute__((ext_vector_type(4)));

#define BB 4
#define HH 240
#define WW 320
#define CG 64
#define NCO 24
#define HWSZ (HH*WW)

__device__ __forceinline__ float ldF(const void* __restrict__ p, long i, int isbf) {
    if (isbf) return __bfloat162float(((const bf16*)p)[i]);
    return ((const float*)p)[i];
}

__device__ __forceinline__ int detect_bf16(const void* asc) {
    // aff_scale_const == 4.0f: fp32 LE low u16 = 0x0000, bf16 = 0x4080.
    return ((const unsigned short*)asc)[0] != 0;
}

__device__ __forceinline__ unsigned short f2bfbits(float v) {
    bf16 h = __float2bfloat16(v);
    return *(unsigned short*)&h;
}

// load 4 consecutive elements as bf16 bits (fp32 path converts; bf16 path copies)
__device__ __forceinline__ void ld4bf(const void* __restrict__ p, long i, int isbf,
                                      unsigned short* __restrict__ o) {
    if (isbf) {
        ushort4 v = *(const ushort4*)((const unsigned short*)p + i);
        o[0] = v.x; o[1] = v.y; o[2] = v.z; o[3] = v.w;
    } else {
        float4 v = *(const float4*)((const float*)p + i);
        o[0] = f2bfbits(v.x); o[1] = f2bfbits(v.y);
        o[2] = f2bfbits(v.z); o[3] = f2bfbits(v.w);
    }
}

// ---------------------------------------------------------------------------
// Kernel 1 (old, channel-major) : emergency fallback path only
// ---------------------------------------------------------------------------
__global__ __launch_bounds__(256) void upsample_kernel(const void* __restrict__ tin,
                                                       const void* __restrict__ asc,
                                                       float* __restrict__ fea) {
    int isbf = detect_bf16(asc);
    int idx = blockIdx.x * 256 + threadIdx.x;
    if (idx >= BB * 8 * HWSZ) return;
    int j = idx % WW;
    int rest = idx / WW;
    int i = rest % HH;
    int bc = rest / HH;
    float sy = 0.5f * (float)i - 0.25f;
    float sx = 0.5f * (float)j - 0.25f;
    float y0f = floorf(sy), x0f = floorf(sx);
    float wy = sy - y0f, wx = sx - x0f;
    int y0 = (int)y0f, x0 = (int)x0f;
    int y0c = min(max(y0, 0), 119), y1c = min(max(y0 + 1, 0), 119);
    int x0c = min(max(x0, 0), 159), x1c = min(max(x0 + 1, 0), 159);
    long base = (long)bc * 120 * 160;
    float v00 = ldF(tin, base + y0c * 160 + x0c, isbf);
    float v01 = ldF(tin, base + y0c * 160 + x1c, isbf);
    float v10 = ldF(tin, base + y1c * 160 + x0c, isbf);
    float v11 = ldF(tin, base + y1c * 160 + x1c, isbf);
    fea[idx] = (1.f - wy) * ((1.f - wx) * v00 + wx * v01)
             + wy * ((1.f - wx) * v10 + wx * v11);
}

// ---------------------------------------------------------------------------
// Kernel 0: tiny NCHW -> NHWC transpose of tgtimg_fea (2.4 MB; coalesced read)
// ---------------------------------------------------------------------------
__global__ __launch_bounds__(256) void tgt_cl_kernel(const void* __restrict__ tin,
                                                     const void* __restrict__ asc,
                                                     float* __restrict__ tcl) {
    int isbf = detect_bf16(asc);
    int idx = blockIdx.x * 256 + threadIdx.x;
    if (idx >= BB * 8 * 120 * 160) return;
    int x = idx % 160;
    int r = idx / 160;
    int yy = r % 120;
    int rc = r / 120;
    int ch = rc % 8;
    int b = rc / 8;
    float v = ldF(tin, idx, isbf);
    tcl[((((size_t)b * 120 + yy) * 160 + x) << 3) + ch] = v;
}

// ---------------------------------------------------------------------------
// Kernel 1b: upsample from channels-last source -> channels-last dest.
// ---------------------------------------------------------------------------
__global__ __launch_bounds__(256) void upsample_cl2_kernel(const float* __restrict__ tcl,
                                                           float* __restrict__ fea_cl) {
    int idx = blockIdx.x * 256 + threadIdx.x;
    if (idx >= BB * HWSZ) return;
    int j = idx % WW;
    int rest = idx / WW;
    int i = rest % HH;
    int b = rest / HH;
    float sy = 0.5f * (float)i - 0.25f;
    float sx = 0.5f * (float)j - 0.25f;
    float y0f = floorf(sy), x0f = floorf(sx);
    float wy = sy - y0f, wx = sx - x0f;
    int y0 = (int)y0f, x0 = (int)x0f;
    int y0c = min(max(y0, 0), 119), y1c = min(max(y0 + 1, 0), 119);
    int x0c = min(max(x0, 0), 159), x1c = min(max(x0 + 1, 0), 159);

    const float* s = tcl + ((size_t)b * 120 * 160) * 8;
    const float* p00 = s + ((size_t)y0c * 160 + x0c) * 8;
    const float* p01 = s + ((size_t)y0c * 160 + x1c) * 8;
    const float* p10 = s + ((size_t)y1c * 160 + x0c) * 8;
    const float* p11 = s + ((size_t)y1c * 160 + x1c) * 8;
    float v00[8], v01[8], v10[8], v11[8], o[8];
    *(float4*)&v00[0] = *(const float4*)p00; *(float4*)&v00[4] = *(const float4*)(p00 + 4);
    *(float4*)&v01[0] = *(const float4*)p01; *(float4*)&v01[4] = *(const float4*)(p01 + 4);
    *(float4*)&v10[0] = *(const float4*)p10; *(float4*)&v10[4] = *(const float4*)(p10 + 4);
    *(float4*)&v11[0] = *(const float4*)p11; *(float4*)&v11[4] = *(const float4*)(p11 + 4);
#pragma unroll
    for (int ch = 0; ch < 8; ch++)
        o[ch] = (1.f - wy) * ((1.f - wx) * v00[ch] + wx * v01[ch])
              + wy * ((1.f - wx) * v10[ch] + wx * v11[ch]);
    float* dst = fea_cl + (size_t)idx * 8;
    *(float4*)dst = make_float4(o[0], o[1], o[2], o[3]);
    *(float4*)(dst + 4) = make_float4(o[4], o[5], o[6], o[7]);
}

// ---------------------------------------------------------------------------
// Prep A (R6): guidance NCHW -> channels-last bf16 gT[b][y][x][ci], vectorized.
// ---------------------------------------------------------------------------
__global__ __launch_bounds__(256) void prep_guidance2(const void* __restrict__ g,
                                                      const void* __restrict__ asc,
                                                      unsigned short* __restrict__ gTu) {
    int isbf = detect_bf16(asc);
    const int x0 = blockIdx.x * 64;
    const int y  = blockIdx.y;
    const int b  = blockIdx.z;
    __shared__ unsigned int sh2[64][33];
    const int t = threadIdx.x;

#pragma unroll
    for (int it = 0; it < 2; it++) {
        int cp = it * 16 + (t >> 4);   // channel pair 0..31
        int xq = t & 15;               // 4-px group 0..15
        long base0 = ((long)(b * CG + 2 * cp) * HH + y) * WW + x0 + 4 * xq;
        long base1 = base0 + (long)HH * WW;
        unsigned short lo[4], hi[4];
        ld4bf(g, base0, isbf, lo);
        ld4bf(g, base1, isbf, hi);
#pragma unroll
        for (int k = 0; k < 4; k++)
            sh2[4 * xq + k][cp] = (unsigned int)lo[k] | ((unsigned int)hi[k] << 16);
    }
    __syncthreads();

#pragma unroll
    for (int it = 0; it < 2; it++) {
        int s = it * 256 + t;
        int xg = s >> 3;      // pixel 0..63
        int cb = s & 7;       // 8-channel block 0..7
        int4 v = make_int4((int)sh2[xg][cb * 4 + 0], (int)sh2[xg][cb * 4 + 1],
                           (int)sh2[xg][cb * 4 + 2], (int)sh2[xg][cb * 4 + 3]);
        *(int4*)&gTu[((((long)b * HH + y) * WW + x0 + xg) << 6) + cb * 8] = v;
    }
}

// ---------------------------------------------------------------------------
// Prep B: weights -> MFMA B-fragment layout Bp[t][n(32, 24 real)][k'(32)] bf16
// ---------------------------------------------------------------------------
__global__ __launch_bounds__(256) void prep_weights(const void* __restrict__ w,
                                                    const void* __restrict__ asc,
                                                    unsigned short* __restrict__ Bpu) {
    int isbf = detect_bf16(asc);
    int idx = blockIdx.x * 256 + threadIdx.x;
    if (idx >= 18 * 32 * 32) return;
    int t = idx >> 10;
    int r = idx & 1023;
    int n = r >> 5;
    int k = r & 31;
    int tap = t >> 1;
    int ch = t & 1;
    float v = 0.f;
    if (n < NCO)
        v = ldF(w, ((long)n * CG + ch * 32 + k) * 9 + tap, isbf);
    Bpu[idx] = f2bfbits(v);
}

// ---------------------------------------------------------------------------
// Kernel 2 (R10): LDS-staged MFMA conv + planes + aff8 + fused cos. 4 rows/blk
// (R9's 2-row split regressed: occupancy rose but halo-FETCH +27% and doubled
// per-block fixed costs won — reverted). R10 removes the oa tensor from the
// full path entirely: offsets ch0-15 live in the 16 out planes (already
// written coalesced), aff logits ch16-23 go to a channels-last aff8 buffer
// (coalesced via shO). Kills 29.5MB of scalar stride-24 oa stores here and
// the 29.5MB oa re-read in final. shO widened to [4][24][67] (25.7KB; union
// with S 16.6KB = 42.4KB fits inside shA's 50.7KB -> occupancy unchanged).
// ---------------------------------------------------------------------------
__global__ __launch_bounds__(256, 4) void conv_mfma5_kernel(const unsigned short* __restrict__ gTu,
                                                            const unsigned short* __restrict__ Bpu,
                                                            const void* __restrict__ bias,
                                                            const void* __restrict__ asc,
                                                            const float* __restrict__ fea_cl,
                                                            float* __restrict__ aff8,
                                                            float* __restrict__ cosb,
                                                            float* __restrict__ out) {
    int isbf = detect_bf16(asc);
    const int x0 = blockIdx.x * 64;
    const int y0 = blockIdx.y * 4;
    const int b  = blockIdx.z;
    const int tid = threadIdx.x;
    const int bx = blockIdx.x;

    __shared__ unsigned short shA[6 * 66 * 64];   // 50688 B union:
    float* shO = (float*)shA;                     //   [4][24][67] f32 = 25728 B
    float* S   = (float*)((char*)shA + 25728);    //   [64][65] f32   = 16640 B

    // ---- stage rows y0-1..y0+4, px x0-1..x0+64, 64 ch bf16 (50688 B) ----
#pragma unroll
    for (int it = 0; it < 13; it++) {
        int s = it * 256 + tid;
        if (s < 3168) {
            int row = s / 528;          // 528 = 66 px * 8 blocks
            int rem = s - row * 528;
            int xi = rem >> 3;
            int blk = rem & 7;
            int y = y0 - 1 + row;
            int x = x0 - 1 + xi;
            int4 v = make_int4(0, 0, 0, 0);
            if (y >= 0 && y < HH && x >= 0 && x < WW)
                v = *(const int4*)(gTu + ((((size_t)b * HH + y) * WW + x) << 6)
                                       + ((blk ^ (xi & 7)) << 3));
            *(int4*)&shA[((row * 66 + xi) << 6) + (blk << 3)] = v;
        }
    }
    __syncthreads();

    const int wid  = tid >> 6;
    const int lane = tid & 63;
    const int m = lane & 15, quad = lane >> 4;

    f32x4 acc0[4], acc1[4];
#pragma unroll
    for (int r = 0; r < 4; r++) {
        acc0[r] = (f32x4){0.f, 0.f, 0.f, 0.f};
        acc1[r] = (f32x4){0.f, 0.f, 0.f, 0.f};
    }

#pragma unroll
    for (int tap = 0; tap < 9; tap++) {
        const int dy = tap / 3, dx = tap % 3;
        const int xi = wid * 16 + m + dx;
#pragma unroll
        for (int h = 0; h < 2; h++) {
            const int t = tap * 2 + h;
            int4 b0i = *(const int4*)(Bpu + ((t * 32 + m) * 32 + quad * 8));
            int4 b1i = *(const int4*)(Bpu + ((t * 32 + 16 + m) * 32 + quad * 8));
            bf16x8 bf0 = __builtin_bit_cast(bf16x8, b0i);
            bf16x8 bf1 = __builtin_bit_cast(bf16x8, b1i);
            const int sw = (((h * 4 + quad) ^ (xi & 7)) << 3);
#pragma unroll
            for (int r = 0; r < 4; r++) {
                int row = r + dy;
                int4 ai = *(const int4*)&shA[(((row * 66 + xi) << 6)) + sw];
                bf16x8 af = __builtin_bit_cast(bf16x8, ai);
                acc0[r] = __builtin_amdgcn_mfma_f32_16x16x32_bf16(af, bf0, acc0[r], 0, 0, 0);
                acc1[r] = __builtin_amdgcn_mfma_f32_16x16x32_bf16(af, bf1, acc1[r], 0, 0, 0);
            }
        }
    }

    const int n = m;
    float bias0 = ldF(bias, n, isbf);
    float bias1 = (n < 8) ? ldF(bias, 16 + n, isbf) : 0.f;
    const int pxl = wid * 16 + quad * 4;   // local px base 0..63

    // ---- stage all 24 output channels into shO (no oa traffic) ----
    __syncthreads();                    // shA reads done; reuse as shO/S
#pragma unroll
    for (int r = 0; r < 4; r++) {
#pragma unroll
        for (int rr = 0; rr < 4; rr++) {
            int pl = pxl + rr;
            shO[(r * 24 + n) * 67 + pl] = acc0[r][rr] + bias0;
            if (n < 8) shO[(r * 24 + 16 + n) * 67 + pl] = acc1[r][rr] + bias1;
        }
    }
    __syncthreads();

    // ---- 16 offset planes of `out`, coalesced: 4096 floats ----
#pragma unroll
    for (int it = 0; it < 16; it++) {
        int s = it * 256 + tid;
        int px = s & 63;
        int rest = s >> 6;
        int nn = rest & 15;
        int r = rest >> 4;
        int och = (nn < 8) ? nn : nn + 2;
        out[(((size_t)b * 18 + och) * HH + (y0 + r)) * WW + x0 + px]
            = shO[(r * 24 + nn) * 67 + px];
    }
    // ---- aff8 channels-last, coalesced: 2048 floats ----
#pragma unroll
    for (int it = 0; it < 8; it++) {
        int s = it * 256 + tid;
        int n8 = s & 7;
        int px = (s >> 3) & 63;
        int r = s >> 9;
        aff8[((((size_t)b * HH + y0 + r) * WW + x0 + px) << 3) + n8]
            = shO[(r * 24 + 16 + n8) * 67 + px];
    }

    // ---- fused cos: per source row r, phase1 gather -> S, then reduce ----
    const float* feaB = fea_cl + (size_t)b * HWSZ * 8;
#pragma unroll 1
    for (int r = 0; r < 4; r++) {
        const int pi = y0 + r;
#pragma unroll
        for (int k = 0; k < 2; k++) {
            int s = k * 256 + tid;
            int c = s >> 6;            // 0..7 (wave-uniform)
            int qj_l = s & 63;
            int qj = x0 + qj_l;
            float ox = shO[(r * 24 + 2 * c) * 67 + qj_l];
            float oy = shO[(r * 24 + 2 * c + 1) * 67 + qj_l];
            float add = (c < 4) ? (float)pi : (float)qj;
            float px = ox + add, py = oy + add;

            float x0f = floorf(px), y0f = floorf(py);
            float wx = px - x0f, wy = py - y0f;
            int xx0 = (int)x0f, yy0 = (int)y0f;
            int x0c = min(max(xx0, 0), WW - 1), x1c = min(max(xx0 + 1, 0), WW - 1);
            int y0c = min(max(yy0, 0), HH - 1), y1c = min(max(yy0 + 1, 0), HH - 1);
            float mx0 = (xx0 == x0c) ? 1.f : 0.f;
            float mx1 = (xx0 + 1 == x1c) ? 1.f : 0.f;
            float my0 = (yy0 == y0c) ? 1.f : 0.f;
            float my1 = (yy0 + 1 == y1c) ? 1.f : 0.f;
            float aw = mx0 * (1.f - wx);
            float bw = mx1 * wx;
            float tw = my0 * (1.f - wy);
            float dw = my1 * wy;

            const float* r0 = feaB + (size_t)y0c * WW * 8;
            const float* r1 = feaB + (size_t)y1c * WW * 8;
            float v00[8], v01[8], v10[8], v11[8];
            *(float4*)&v00[0] = *(const float4*)(r0 + x0c * 8);
            *(float4*)&v00[4] = *(const float4*)(r0 + x0c * 8 + 4);
            *(float4*)&v01[0] = *(const float4*)(r0 + x1c * 8);
            *(float4*)&v01[4] = *(const float4*)(r0 + x1c * 8 + 4);
            *(float4*)&v10[0] = *(const float4*)(r1 + x0c * 8);
            *(float4*)&v10[4] = *(const float4*)(r1 + x0c * 8 + 4);
            *(float4*)&v11[0] = *(const float4*)(r1 + x1c * 8);
            *(float4*)&v11[4] = *(const float4*)(r1 + x1c * 8 + 4);

            int base = qj_l * 65 + c * 8;
#pragma unroll
            for (int ch = 0; ch < 8; ch++)
                S[base + ch] = tw * (aw * v00[ch] + bw * v01[ch])
                             + dw * (aw * v10[ch] + bw * v11[ch]);
        }
        __syncthreads();

        {
            int pix = tid >> 2;     // 0..63: (g, c_img)
            int cp  = tid & 3;      // computes c = 2cp, 2cp+1
            int g = pix >> 3;
            int c_img = pix & 7;
            int i = c_img * 30 + (pi >> 3);
            int j = (pi & 7) * 40 + bx * 8 + g;
            const float* fp = feaB + ((size_t)i * WW + j) * 8;
            float f[8];
            *(float4*)&f[0] = *(const float4*)fp;
            *(float4*)&f[4] = *(const float4*)(fp + 4);
            float a0 = 0.f, a1 = 0.f;
            int c0 = 2 * cp;
#pragma unroll
            for (int nn = 0; nn < 8; nn++) {   // ascending n: same FP order
                float fn = f[nn];
                int rb = (8 * g + nn) * 65 + c_img;
                a0 += fn * S[rb + c0 * 8];
                a1 += fn * S[rb + (c0 + 1) * 8];
            }
            float* dst = cosb + (((size_t)b * HH + i) * WW + j) * 8 + c0;
            *(float2*)dst = make_float2(a0, a1);
        }
        __syncthreads();
    }
}

// ---------------------------------------------------------------------------
// Fallback scalar conv (only if ws too small for gTu).
// ---------------------------------------------------------------------------
__global__ __launch_bounds__(256, 4) void conv_fallback(const void* __restrict__ g,
                                                        const void* __restrict__ w,
                                                        const void* __restrict__ bias,
                                                        const void* __restrict__ asc,
                                                        float* __restrict__ oa) {
    int isbf = detect_bf16(asc);
    const int b = blockIdx.z;
    const int i0 = blockIdx.y * 16;
    const int j0 = blockIdx.x * 16;
    const int tx = threadIdx.x & 15;
    const int ty = threadIdx.x >> 4;

    __shared__ float gl[8][18][20];
    __shared__ float wl[8][NCO][10];

    float acc[NCO];
#pragma unroll
    for (int c = 0; c < NCO; c++) acc[c] = ldF(bias, c, isbf);

    for (int ci0 = 0; ci0 < CG; ci0 += 8) {
        __syncthreads();
        for (int idx = threadIdx.x; idx < 8 * NCO * 9; idx += 256) {
            int t = idx % 9;
            int rest = idx / 9;
            int cc = rest & 7;
            int co = rest >> 3;
            wl[cc][co][t] = ldF(w, (long)(co * CG + ci0 + cc) * 9 + t, isbf);
        }
        for (int idx = threadIdx.x; idx < 8 * 18 * 18; idx += 256) {
            int cc = idx / 324;
            int rem = idx - cc * 324;
            int r = rem / 18;
            int c2 = rem - r * 18;
            int gi = i0 - 1 + r;
            int gj = j0 - 1 + c2;
            float v = 0.f;
            if (gi >= 0 && gi < HH && gj >= 0 && gj < WW)
                v = ldF(g, ((long)(b * CG + ci0 + cc) * HH + gi) * WW + gj, isbf);
            gl[cc][r][c2] = v;
        }
        __syncthreads();
#pragma unroll
        for (int cc = 0; cc < 8; cc++) {
            float ga[9];
#pragma unroll
            for (int dy = 0; dy < 3; dy++)
#pragma unroll
                for (int dx = 0; dx < 3; dx++)
                    ga[dy * 3 + dx] = gl[cc][ty + dy][tx + dx];
#pragma unroll 4
            for (int co = 0; co < NCO; co++) {
                float s = 0.f;
#pragma unroll
                for (int t = 0; t < 9; t++)
                    s += wl[cc][co][t] * ga[t];
                acc[co] += s;
            }
        }
    }
    int i = i0 + ty, j = j0 + tx;
    float4* p = (float4*)&oa[(((size_t)b * HH + i) * WW + j) * NCO];
#pragma unroll
    for (int q = 0; q < 6; q++)
        p[q] = make_float4(acc[4 * q], acc[4 * q + 1], acc[4 * q + 2], acc[4 * q + 3]);
}

// ---------------------------------------------------------------------------
// Branchless bilinear, zero outside: clamp indices, mask corner weights.
// ---------------------------------------------------------------------------
__device__ __forceinline__ float bil_zero_f32(const float* __restrict__ img,
                                              float x, float y) {
    float x0f = floorf(x), y0f = floorf(y);
    float wx = x - x0f, wy = y - y0f;
    int x0 = (int)x0f, y0 = (int)y0f;
    int x0c = min(max(x0, 0), WW - 1), x1c = min(max(x0 + 1, 0), WW - 1);
    int y0c = min(max(y0, 0), HH - 1), y1c = min(max(y0 + 1, 0), HH - 1);
    float mx0 = (x0 == x0c) ? 1.f : 0.f;
    float mx1 = (x0 + 1 == x1c) ? 1.f : 0.f;
    float my0 = (y0 == y0c) ? 1.f : 0.f;
    float my1 = (y0 + 1 == y1c) ? 1.f : 0.f;
    const float* r0 = img + (size_t)y0c * WW;
    const float* r1 = img + (size_t)y1c * WW;
    float v00 = r0[x0c], v01 = r0[x1c], v10 = r1[x0c], v11 = r1[x1c];
    return my0 * (1.f - wy) * (mx0 * (1.f - wx) * v00 + mx1 * wx * v01)
         + my1 * wy * (mx0 * (1.f - wx) * v10 + mx1 * wx * v11);
}

__device__ __forceinline__ float bil_zero_poly(const void* __restrict__ img, long base,
                                               float x, float y, int isbf) {
    float x0f = floorf(x), y0f = floorf(y);
    float wx = x - x0f, wy = y - y0f;
    int x0 = (int)x0f, y0 = (int)y0f;
    int x0c = min(max(x0, 0), WW - 1), x1c = min(max(x0 + 1, 0), WW - 1);
    int y0c = min(max(y0, 0), HH - 1), y1c = min(max(y0 + 1, 0), HH - 1);
    float mx0 = (x0 == x0c) ? 1.f : 0.f;
    float mx1 = (x0 + 1 == x1c) ? 1.f : 0.f;
    float my0 = (y0 == y0c) ? 1.f : 0.f;
    float my1 = (y0 + 1 == y1c) ? 1.f : 0.f;
    long r0 = base + (long)y0c * WW;
    long r1 = base + (long)y1c * WW;
    float v00 = ldF(img, r0 + x0c, isbf), v01 = ldF(img, r0 + x1c, isbf);
    float v10 = ldF(img, r1 + x0c, isbf), v11 = ldF(img, r1 + x1c, isbf);
    return my0 * (1.f - wy) * (mx0 * (1.f - wx) * v00 + mx1 * wx * v01)
         + my1 * wy * (mx0 * (1.f - wx) * v10 + mx1 * wx * v11);
}

// ---------------------------------------------------------------------------
// Kernel 3a (mid path only): source-centric cosine affinity.
// ---------------------------------------------------------------------------
__global__ __launch_bounds__(256, 4) void cos_kernel(const float* __restrict__ oa,
                                                     const float* __restrict__ fea_cl,
                                                     float* __restrict__ cos_buf) {
    __shared__ float S_lds[64 * 65];
    const int bx = blockIdx.x;   // 0..4 (qj chunk of 64)
    const int pi = blockIdx.y;   // 0..239
    const int b  = blockIdx.z;
    const int tid = threadIdx.x;
    const int qj_l = tid & 63;
    const int cpair = tid >> 6;  // 0..3 -> c in {2cp, 2cp+1}
    const int qj = bx * 64 + qj_l;

    const float* feaB = fea_cl + (size_t)b * HWSZ * 8;
    const float4 ov = *(const float4*)&oa[(((size_t)b * HH + pi) * WW + qj) * NCO + 4 * cpair];

#pragma unroll
    for (int t = 0; t < 2; t++) {
        int c = 2 * cpair + t;
        float ox = (t == 0) ? ov.x : ov.z;
        float oy = (t == 0) ? ov.y : ov.w;
        float add = (c < 4) ? (float)pi : (float)qj;   // wave-uniform branch
        float px = ox + add, py = oy + add;

        float x0f = floorf(px), y0f = floorf(py);
        float wx = px - x0f, wy = py - y0f;
        int x0 = (int)x0f, y0 = (int)y0f;
        int x0c = min(max(x0, 0), WW - 1), x1c = min(max(x0 + 1, 0), WW - 1);
        int y0c = min(max(y0, 0), HH - 1), y1c = min(max(y0 + 1, 0), HH - 1);
        float mx0 = (x0 == x0c) ? 1.f : 0.f;
        float mx1 = (x0 + 1 == x1c) ? 1.f : 0.f;
        float my0 = (y0 == y0c) ? 1.f : 0.f;
        float my1 = (y0 + 1 == y1c) ? 1.f : 0.f;
        float aw = mx0 * (1.f - wx);
        float bw = mx1 * wx;
        float tw = my0 * (1.f - wy);
        float dw = my1 * wy;

        const float* r0 = feaB + (size_t)y0c * WW * 8;
        const float* r1 = feaB + (size_t)y1c * WW * 8;
        float v00[8], v01[8], v10[8], v11[8];
        *(float4*)&v00[0] = *(const float4*)(r0 + x0c * 8);
        *(float4*)&v00[4] = *(const float4*)(r0 + x0c * 8 + 4);
        *(float4*)&v01[0] = *(const float4*)(r0 + x1c * 8);
        *(float4*)&v01[4] = *(const float4*)(r0 + x1c * 8 + 4);
        *(float4*)&v10[0] = *(const float4*)(r1 + x0c * 8);
        *(float4*)&v10[4] = *(const float4*)(r1 + x0c * 8 + 4);
        *(float4*)&v11[0] = *(const float4*)(r1 + x1c * 8);
        *(float4*)&v11[4] = *(const float4*)(r1 + x1c * 8 + 4);

        int base = qj_l * 65 + c * 8;
#pragma unroll
        for (int ch = 0; ch < 8; ch++)
            S_lds[base + ch] = tw * (aw * v00[ch] + bw * v01[ch])
                             + dw * (aw * v10[ch] + bw * v11[ch]);
    }

    __syncthreads();

    {
        int pix = tid >> 2;     // 0..63: (g, c_img)
        int cp  = tid & 3;      // computes c = 2cp, 2cp+1
        int g = pix >> 3;
        int c_img = pix & 7;
        int i = c_img * 30 + (pi >> 3);
        int j = (pi & 7) * 40 + bx * 8 + g;
        const float* fp = feaB + ((size_t)i * WW + j) * 8;
        float f[8];
        *(float4*)&f[0] = *(const float4*)fp;
        *(float4*)&f[4] = *(const float4*)(fp + 4);
        float a0 = 0.f, a1 = 0.f;
        int c0 = 2 * cp;
#pragma unroll
        for (int n = 0; n < 8; n++) {       // ascending n: same FP order
            float fn = f[n];
            int rb = (8 * g + n) * 65 + c_img;
            a0 += fn * S_lds[rb + c0 * 8];
            a1 += fn * S_lds[rb + (c0 + 1) * 8];
        }
        float* dst = cos_buf + (((size_t)b * HH + i) * WW + j) * 8 + c0;
        *(float2*)dst = make_float2(a0, a1);
    }
}

// ---------------------------------------------------------------------------
// Kernel 3b (R10, full path): epilogue reading offsets from out planes +
// aff logits from aff8 (oa eliminated). Fast tanh (saturating, err ~1e-7).
// ---------------------------------------------------------------------------
__global__ __launch_bounds__(256, 4) void final4_kernel(const float* __restrict__ aff8,
                                                        const float* __restrict__ cos_buf,
                                                        const void* __restrict__ conf_in,
                                                        const void* __restrict__ asc_p,
                                                        float* __restrict__ out) {
    int isbf = detect_bf16(asc_p);
    int idx = blockIdx.x * 256 + threadIdx.x;
    if (idx >= BB * HWSZ) return;
    int j = idx % WW;
    int rest = idx / WW;
    int i = rest % HH;
    int b = rest / HH;

    float cos_acc[8];
    {
        const float* cp = cos_buf + (size_t)idx * 8;
        float4 ca = *(const float4*)cp;
        float4 cb = *(const float4*)(cp + 4);
        cos_acc[0] = ca.x; cos_acc[1] = ca.y; cos_acc[2] = ca.z; cos_acc[3] = ca.w;
        cos_acc[4] = cb.x; cos_acc[5] = cb.y; cos_acc[6] = cb.z; cos_acc[7] = cb.w;
    }
    float affl[8];
    {
        const float* ap = aff8 + (size_t)idx * 8;
        float4 aa = *(const float4*)ap;
        float4 ab = *(const float4*)(ap + 4);
        affl[0] = aa.x; affl[1] = aa.y; affl[2] = aa.z; affl[3] = aa.w;
        affl[4] = ab.x; affl[5] = ab.y; affl[6] = ab.z; affl[7] = ab.w;
    }
    // offsets ch0..15 from the 16 out planes (coalesced; L2-warm, just written)
    size_t pix = (size_t)i * WW + j;
    float offs[16];
#pragma unroll
    for (int ch = 0; ch < 16; ch++) {
        int och = (ch < 8) ? ch : ch + 2;
        offs[ch] = out[((size_t)b * 18 + och) * HWSZ + pix];
    }

    float asc = ldF(asc_p, 0, isbf) + 1e-8f;
    long cbase = (long)b * HWSZ;

    float a[8];
    float ssum = 0.f;
#pragma unroll
    for (int c = 0; c < 8; c++) {
        float v = affl[c] * cos_acc[c];
        float e2 = __expf(2.f * v);
        v = (1.f - 2.f / (e2 + 1.f)) / asc;
        float py2 = offs[2 * c] + (float)i;
        float px2 = offs[2 * c + 1] + (float)j;
        float cf = bil_zero_poly(conf_in, cbase, px2, py2, isbf);
        v *= cf;
        a[c] = v;
        ssum += fabsf(v);
    }
    ssum += 1e-4f;
    ssum = fmaxf(ssum, 1.0f);
    float inv = 1.0f / ssum;
    float asum = 0.f;
#pragma unroll
    for (int c = 0; c < 8; c++) { a[c] *= inv; asum += a[c]; }
    float aref = 1.0f - asum;

    float vals[9];
#pragma unroll
    for (int c = 0; c < 4; c++) vals[c] = a[c];
    vals[4] = aref;
#pragma unroll
    for (int c = 4; c < 8; c++) vals[c + 1] = a[c];
    float m = vals[0];
#pragma unroll
    for (int k = 1; k < 9; k++) m = fmaxf(m, vals[k]);
    float es = 0.f;
#pragma unroll
    for (int k = 0; k < 9; k++) { vals[k] = __expf(vals[k] - m); es += vals[k]; }
    float ei = 1.0f / es;

    size_t base_o = (size_t)b * 18 * HWSZ + pix;
    out[base_o + (size_t)8 * HWSZ] = 0.f;     // zref planes
    out[base_o + (size_t)9 * HWSZ] = 0.f;
    float* aff_out = out + (size_t)BB * 18 * HWSZ;
    size_t base_a = (size_t)b * 9 * HWSZ + pix;
#pragma unroll
    for (int k = 0; k < 9; k++)
        aff_out[base_a + (size_t)k * HWSZ] = vals[k] * ei;
}

// ---------------------------------------------------------------------------
// Kernel 3b (mid path): full epilogue incl. all 18 offset planes (uses oa).
// ---------------------------------------------------------------------------
__global__ __launch_bounds__(256, 4) void final2_kernel(const float* __restrict__ oa,
                                                        const float* __restrict__ cos_buf,
                                                        const void* __restrict__ conf_in,
                                                        const void* __restrict__ asc_p,
                                                        float* __restrict__ out) {
    int isbf = detect_bf16(asc_p);
    int idx = blockIdx.x * 256 + threadIdx.x;
    if (idx >= BB * HWSZ) return;
    int j = idx % WW;
    int rest = idx / WW;
    int i = rest % HH;
    int b = rest / HH;

    float cos_acc[8];
    {
        const float* cp = cos_buf + (size_t)idx * 8;
        float4 ca = *(const float4*)cp;
        float4 cb = *(const float4*)(cp + 4);
        cos_acc[0] = ca.x; cos_acc[1] = ca.y; cos_acc[2] = ca.z; cos_acc[3] = ca.w;
        cos_acc[4] = cb.x; cos_acc[5] = cb.y; cos_acc[6] = cb.z; cos_acc[7] = cb.w;
    }

    const float4* op = (const float4*)&oa[(((size_t)b * HH + i) * WW + j) * NCO];
    float own[24];
#pragma unroll
    for (int q = 0; q < 6; q++) {
        float4 v = op[q];
        own[4 * q] = v.x; own[4 * q + 1] = v.y; own[4 * q + 2] = v.z; own[4 * q + 3] = v.w;
    }

    float asc = ldF(asc_p, 0, isbf) + 1e-8f;
    long cbase = (long)b * HWSZ;

    float a[8];
    float ssum = 0.f;
#pragma unroll
    for (int c = 0; c < 8; c++) {
        float v = own[16 + c] * cos_acc[c];
        v = tanhf(v) / asc;
        float py2 = own[2 * c] + (float)i;
        float px2 = own[2 * c + 1] + (float)j;
        float cf = bil_zero_poly(conf_in, cbase, px2, py2, isbf);
        v *= cf;
        a[c] = v;
        ssum += fabsf(v);
    }
    ssum += 1e-4f;
    ssum = fmaxf(ssum, 1.0f);
    float inv = 1.0f / ssum;
    float asum = 0.f;
#pragma unroll
    for (int c = 0; c < 8; c++) { a[c] *= inv; asum += a[c]; }
    float aref = 1.0f - asum;

    float vals[9];
#pragma unroll
    for (int c = 0; c < 4; c++) vals[c] = a[c];
    vals[4] = aref;
#pragma unroll
    for (int c = 4; c < 8; c++) vals[c + 1] = a[c];
    float m = vals[0];
#pragma unroll
    for (int k = 1; k < 9; k++) m = fmaxf(m, vals[k]);
    float es = 0.f;
#pragma unroll
    for (int k = 0; k < 9; k++) { vals[k] = __expf(vals[k] - m); es += vals[k]; }
    float ei = 1.0f / es;

    size_t pix = (size_t)i * WW + j;
    size_t base_o = (size_t)b * 18 * HWSZ + pix;
#pragma unroll
    for (int ch = 0; ch < 18; ch++) {
        float v;
        if (ch < 8) v = own[ch];
        else if (ch < 10) v = 0.f;
        else v = own[ch - 2];
        out[base_o + (size_t)ch * HWSZ] = v;
    }
    float* aff_out = out + (size_t)BB * 18 * HWSZ;
    size_t base_a = (size_t)b * 9 * HWSZ + pix;
#pragma unroll
    for (int k = 0; k < 9; k++)
        aff_out[base_a + (size_t)k * HWSZ] = vals[k] * ei;
}

// ---------------------------------------------------------------------------
// OLD monolithic final kernel — emergency fallback only (tiny workspace).
// ---------------------------------------------------------------------------
__global__ __launch_bounds__(256, 4) void final_kernel(const float* __restrict__ oa,
                                                       const float* __restrict__ fea,
                                                       const void* __restrict__ conf_in,
                                                       const void* __restrict__ asc_p,
                                                       float* __restrict__ out) {
    int isbf = detect_bf16(asc_p);
    int idx = blockIdx.x * 256 + threadIdx.x;
    if (idx >= BB * HWSZ) return;
    int j = idx % WW;
    int rest = idx / WW;
    int i = rest % HH;
    int b = rest / HH;

    const float* feaB = fea + (size_t)b * 8 * HWSZ;
    float f[8];
#pragma unroll
    for (int n = 0; n < 8; n++)
        f[n] = feaB[(size_t)n * HWSZ + (size_t)i * WW + j];

    int c_img = i / 30;
    int pi = (i % 30) * 8 + j / 40;
    int pj0 = (j % 40) * 8;
    const float* feaC = feaB + (size_t)c_img * HWSZ;

    float cos_acc[8];
#pragma unroll
    for (int c = 0; c < 8; c++) cos_acc[c] = 0.f;

#pragma unroll 1
    for (int n = 0; n < 8; n++) {
        int qj = pj0 + n;
        const float4* oq = (const float4*)&oa[(((size_t)b * HH + pi) * WW + qj) * NCO];
        float4 o0 = oq[0], o1 = oq[1], o2 = oq[2], o3 = oq[3];
        float off[16] = {o0.x, o0.y, o0.z, o0.w, o1.x, o1.y, o1.z, o1.w,
                         o2.x, o2.y, o2.z, o2.w, o3.x, o3.y, o3.z, o3.w};
        float fn = f[n];
#pragma unroll
        for (int c = 0; c < 8; c++) {
            float add = (c < 4) ? (float)pi : (float)qj;
            float px = off[2 * c] + add;
            float py = off[2 * c + 1] + add;
            cos_acc[c] += fn * bil_zero_f32(feaC, px, py);
        }
    }

    const float4* op = (const float4*)&oa[(((size_t)b * HH + i) * WW + j) * NCO];
    float own[24];
#pragma unroll
    for (int q = 0; q < 6; q++) {
        float4 v = op[q];
        own[4 * q] = v.x; own[4 * q + 1] = v.y; own[4 * q + 2] = v.z; own[4 * q + 3] = v.w;
    }

    float asc = ldF(asc_p, 0, isbf) + 1e-8f;
    long cbase = (long)b * HWSZ;

    float a[8];
    float ssum = 0.f;
#pragma unroll
    for (int c = 0; c < 8; c++) {
        float v = own[16 + c] * cos_acc[c];
        v = tanhf(v) / asc;
        float py2 = own[2 * c] + (float)i;
        float px2 = own[2 * c + 1] + (float)j;
        float cf = bil_zero_poly(conf_in, cbase, px2, py2, isbf);
        v *= cf;
        a[c] = v;
        ssum += fabsf(v);
    }
    ssum += 1e-4f;
    ssum = fmaxf(ssum, 1.0f);
    float inv = 1.0f / ssum;
    float asum = 0.f;
#pragma unroll
    for (int c = 0; c < 8; c++) { a[c] *= inv; asum += a[c]; }
    float aref = 1.0f - asum;

    float vals[9];
#pragma unroll
    for (int c = 0; c < 4; c++) vals[c] = a[c];
    vals[4] = aref;
#pragma unroll
    for (int c = 4; c < 8; c++) vals[c + 1] = a[c];
    float m = vals[0];
#pragma unroll
    for (int k = 1; k < 9; k++) m = fmaxf(m, vals[k]);
    float es = 0.f;
#pragma unroll
    for (int k = 0; k < 9; k++) { vals[k] = __expf(vals[k] - m); es += vals[k]; }
    float ei = 1.0f / es;

    size_t pix = (size_t)i * WW + j;
    size_t base_o = (size_t)b * 18 * HWSZ + pix;
#pragma unroll
    for (int ch = 0; ch < 18; ch++) {
        float v;
        if (ch < 8) v = own[ch];
        else if (ch < 10) v = 0.f;
        else v = own[ch - 2];
        out[base_o + (size_t)ch * HWSZ] = v;
    }
    float* aff_out = out + (size_t)BB * 18 * HWSZ;
    size_t base_a = (size_t)b * 9 * HWSZ + pix;
#pragma unroll
    for (int k = 0; k < 9; k++)
        aff_out[base_a + (size_t)k * HWSZ] = vals[k] * ei;
}

// ---------------------------------------------------------------------------
extern "C" void kernel_launch(void* const* d_in, const int* in_sizes, int n_in,
                              void* d_out, int out_size, void* d_ws, size_t ws_size,
                              hipStream_t stream) {
    const void* guidance = d_in[0];
    const void* gtconf   = d_in[1];
    const void* tgt      = d_in[2];
    const void* conv_w   = d_in[3];
    const void* conv_b   = d_in[4];
    const void* asc      = d_in[5];

    // Workspace layout (full path no longer uses oa; its region hosts aff8):
    //   oa/aff8 : 29,491,200 B (aff8 uses first 9.8 MB in full path)
    //   fea     :  9,830,400 B
    //   cosb    :  9,830,400 B
    //   big     : 39,321,600 B (tcl | gTu time-shared)
    //   Bpu     :     36,864 B
    float* oa   = (float*)d_ws;
    float* aff8 = oa;                       // full path alias (oa unused there)
    float* fea  = oa + (size_t)BB * HWSZ * NCO;
    float* cosb = fea + (size_t)BB * 8 * HWSZ;
    float* big  = cosb + (size_t)BB * 8 * HWSZ;
    unsigned short* gTu = (unsigned short*)big;
    float* tcl  = big;
    unsigned short* Bpu = (unsigned short*)((char*)big + (size_t)39321600);
    const size_t ws_full = (size_t)29491200 + 9830400 + 9830400 + 39321600 + 36864; // 88,510,464
    const size_t ws_mid  = (size_t)29491200 + 9830400 + 9830400;                    // 49,152,000
    float* out = (float*)d_out;

    int n_pix = BB * HWSZ;
    int n_tgt = BB * 8 * 120 * 160;

    if (ws_size >= ws_full) {
        tgt_cl_kernel<<<(n_tgt + 255) / 256, 256, 0, stream>>>(tgt, asc, tcl);
        upsample_cl2_kernel<<<(n_pix + 255) / 256, 256, 0, stream>>>(tcl, fea);
        prep_weights<<<72, 256, 0, stream>>>(conv_w, asc, Bpu);
        dim3 pgrid(WW / 64, HH, BB);
        prep_guidance2<<<pgrid, 256, 0, stream>>>(guidance, asc, gTu);
        dim3 cgrid(WW / 64, HH / 4, BB);
        conv_mfma5_kernel<<<cgrid, 256, 0, stream>>>(gTu, Bpu, conv_b, asc, fea,
                                                     aff8, cosb, out);
        final4_kernel<<<(n_pix + 255) / 256, 256, 0, stream>>>(aff8, cosb, gtconf, asc, out);
    } else if (ws_size >= ws_mid) {
        // mid path: no gTu; scalar conv + split cos/final2 (uses oa). tcl
        // aliases cosb (disjoint liveness).
        float* tclm = cosb;
        tgt_cl_kernel<<<(n_tgt + 255) / 256, 256, 0, stream>>>(tgt, asc, tclm);
        upsample_cl2_kernel<<<(n_pix + 255) / 256, 256, 0, stream>>>(tclm, fea);
        dim3 cgrid(WW / 16, HH / 16, BB);
        conv_fallback<<<cgrid, 256, 0, stream>>>(guidance, conv_w, conv_b, asc, oa);
        dim3 ggrid(WW / 64, HH, BB);
        cos_kernel<<<ggrid, 256, 0, stream>>>(oa, fea, cosb);
        final2_kernel<<<(n_pix + 255) / 256, 256, 0, stream>>>(oa, cosb, gtconf, asc, out);
    } else {
        // --- emergency tiny-workspace path (old monolithic) ---
        int n_up = BB * 8 * HWSZ;
        upsample_kernel<<<(n_up + 255) / 256, 256, 0, stream>>>(tgt, asc, fea);
        dim3 cgrid(WW / 16, HH / 16, BB);
        conv_fallback<<<cgrid, 256, 0, stream>>>(guidance, conv_w, conv_b, asc, oa);
        final_kernel<<<(n_pix + 255) / 256, 256, 0, stream>>>(oa, fea, gtconf, asc, out);
    }
}

// Round 11
// 215.159 us; speedup vs baseline: 1.0533x; 1.0098x over previous
//
#include <hip/hip_runtime.h>
#include <hip/hip_bf16.h>

typedef __hip_bfloat16 bf16;
typedef __bf16 bf16x8 __attribute__((ext_vector_type(8)));
typedef float f32x4 __attribute__((ext_vector_type(4)));

#define BB 4
#define HH 240
#define WW 320
#define CG 64
#define NCO 24
#define HWSZ (HH*WW)

__device__ __forceinline__ float ldF(const void* __restrict__ p, long i, int isbf) {
    if (isbf) return __bfloat162float(((const bf16*)p)[i]);
    return ((const float*)p)[i];
}

__device__ __forceinline__ int detect_bf16(const void* asc) {
    // aff_scale_const == 4.0f: fp32 LE low u16 = 0x0000, bf16 = 0x4080.
    return ((const unsigned short*)asc)[0] != 0;
}

__device__ __forceinline__ unsigned short f2bfbits(float v) {
    bf16 h = __float2bfloat16(v);
    return *(unsigned short*)&h;
}

// load 4 consecutive elements as bf16 bits (fp32 path converts; bf16 path copies)
__device__ __forceinline__ void ld4bf(const void* __restrict__ p, long i, int isbf,
                                      unsigned short* __restrict__ o) {
    if (isbf) {
        ushort4 v = *(const ushort4*)((const unsigned short*)p + i);
        o[0] = v.x; o[1] = v.y; o[2] = v.z; o[3] = v.w;
    } else {
        float4 v = *(const float4*)((const float*)p + i);
        o[0] = f2bfbits(v.x); o[1] = f2bfbits(v.y);
        o[2] = f2bfbits(v.z); o[3] = f2bfbits(v.w);
    }
}

// ---------------------------------------------------------------------------
// Kernel 1 (old, channel-major) : emergency fallback path only
// ---------------------------------------------------------------------------
__global__ __launch_bounds__(256) void upsample_kernel(const void* __restrict__ tin,
                                                       const void* __restrict__ asc,
                                                       float* __restrict__ fea) {
    int isbf = detect_bf16(asc);
    int idx = blockIdx.x * 256 + threadIdx.x;
    if (idx >= BB * 8 * HWSZ) return;
    int j = idx % WW;
    int rest = idx / WW;
    int i = rest % HH;
    int bc = rest / HH;
    float sy = 0.5f * (float)i - 0.25f;
    float sx = 0.5f * (float)j - 0.25f;
    float y0f = floorf(sy), x0f = floorf(sx);
    float wy = sy - y0f, wx = sx - x0f;
    int y0 = (int)y0f, x0 = (int)x0f;
    int y0c = min(max(y0, 0), 119), y1c = min(max(y0 + 1, 0), 119);
    int x0c = min(max(x0, 0), 159), x1c = min(max(x0 + 1, 0), 159);
    long base = (long)bc * 120 * 160;
    float v00 = ldF(tin, base + y0c * 160 + x0c, isbf);
    float v01 = ldF(tin, base + y0c * 160 + x1c, isbf);
    float v10 = ldF(tin, base + y1c * 160 + x0c, isbf);
    float v11 = ldF(tin, base + y1c * 160 + x1c, isbf);
    fea[idx] = (1.f - wy) * ((1.f - wx) * v00 + wx * v01)
             + wy * ((1.f - wx) * v10 + wx * v11);
}

// ---------------------------------------------------------------------------
// Kernel 0: tiny NCHW -> NHWC transpose of tgtimg_fea (2.4 MB; coalesced read)
// ---------------------------------------------------------------------------
__global__ __launch_bounds__(256) void tgt_cl_kernel(const void* __restrict__ tin,
                                                     const void* __restrict__ asc,
                                                     float* __restrict__ tcl) {
    int isbf = detect_bf16(asc);
    int idx = blockIdx.x * 256 + threadIdx.x;
    if (idx >= BB * 8 * 120 * 160) return;
    int x = idx % 160;
    int r = idx / 160;
    int yy = r % 120;
    int rc = r / 120;
    int ch = rc % 8;
    int b = rc / 8;
    float v = ldF(tin, idx, isbf);
    tcl[((((size_t)b * 120 + yy) * 160 + x) << 3) + ch] = v;
}

// ---------------------------------------------------------------------------
// Kernel 1b: upsample from channels-last source -> channels-last dest.
// ---------------------------------------------------------------------------
__global__ __launch_bounds__(256) void upsample_cl2_kernel(const float* __restrict__ tcl,
                                                           float* __restrict__ fea_cl) {
    int idx = blockIdx.x * 256 + threadIdx.x;
    if (idx >= BB * HWSZ) return;
    int j = idx % WW;
    int rest = idx / WW;
    int i = rest % HH;
    int b = rest / HH;
    float sy = 0.5f * (float)i - 0.25f;
    float sx = 0.5f * (float)j - 0.25f;
    float y0f = floorf(sy), x0f = floorf(sx);
    float wy = sy - y0f, wx = sx - x0f;
    int y0 = (int)y0f, x0 = (int)x0f;
    int y0c = min(max(y0, 0), 119), y1c = min(max(y0 + 1, 0), 119);
    int x0c = min(max(x0, 0), 159), x1c = min(max(x0 + 1, 0), 159);

    const float* s = tcl + ((size_t)b * 120 * 160) * 8;
    const float* p00 = s + ((size_t)y0c * 160 + x0c) * 8;
    const float* p01 = s + ((size_t)y0c * 160 + x1c) * 8;
    const float* p10 = s + ((size_t)y1c * 160 + x0c) * 8;
    const float* p11 = s + ((size_t)y1c * 160 + x1c) * 8;
    float v00[8], v01[8], v10[8], v11[8], o[8];
    *(float4*)&v00[0] = *(const float4*)p00; *(float4*)&v00[4] = *(const float4*)(p00 + 4);
    *(float4*)&v01[0] = *(const float4*)p01; *(float4*)&v01[4] = *(const float4*)(p01 + 4);
    *(float4*)&v10[0] = *(const float4*)p10; *(float4*)&v10[4] = *(const float4*)(p10 + 4);
    *(float4*)&v11[0] = *(const float4*)p11; *(float4*)&v11[4] = *(const float4*)(p11 + 4);
#pragma unroll
    for (int ch = 0; ch < 8; ch++)
        o[ch] = (1.f - wy) * ((1.f - wx) * v00[ch] + wx * v01[ch])
              + wy * ((1.f - wx) * v10[ch] + wx * v11[ch]);
    float* dst = fea_cl + (size_t)idx * 8;
    *(float4*)dst = make_float4(o[0], o[1], o[2], o[3]);
    *(float4*)(dst + 4) = make_float4(o[4], o[5], o[6], o[7]);
}

// ---------------------------------------------------------------------------
// Prep A (R6): guidance NCHW -> channels-last bf16 gT[b][y][x][ci], vectorized.
// ---------------------------------------------------------------------------
__global__ __launch_bounds__(256) void prep_guidance2(const void* __restrict__ g,
                                                      const void* __restrict__ asc,
                                                      unsigned short* __restrict__ gTu) {
    int isbf = detect_bf16(asc);
    const int x0 = blockIdx.x * 64;
    const int y  = blockIdx.y;
    const int b  = blockIdx.z;
    __shared__ unsigned int sh2[64][33];
    const int t = threadIdx.x;

#pragma unroll
    for (int it = 0; it < 2; it++) {
        int cp = it * 16 + (t >> 4);   // channel pair 0..31
        int xq = t & 15;               // 4-px group 0..15
        long base0 = ((long)(b * CG + 2 * cp) * HH + y) * WW + x0 + 4 * xq;
        long base1 = base0 + (long)HH * WW;
        unsigned short lo[4], hi[4];
        ld4bf(g, base0, isbf, lo);
        ld4bf(g, base1, isbf, hi);
#pragma unroll
        for (int k = 0; k < 4; k++)
            sh2[4 * xq + k][cp] = (unsigned int)lo[k] | ((unsigned int)hi[k] << 16);
    }
    __syncthreads();

#pragma unroll
    for (int it = 0; it < 2; it++) {
        int s = it * 256 + t;
        int xg = s >> 3;      // pixel 0..63
        int cb = s & 7;       // 8-channel block 0..7
        int4 v = make_int4((int)sh2[xg][cb * 4 + 0], (int)sh2[xg][cb * 4 + 1],
                           (int)sh2[xg][cb * 4 + 2], (int)sh2[xg][cb * 4 + 3]);
        *(int4*)&gTu[((((long)b * HH + y) * WW + x0 + xg) << 6) + cb * 8] = v;
    }
}

// ---------------------------------------------------------------------------
// Prep B: weights -> MFMA B-fragment layout Bp[t][n(32, 24 real)][k'(32)] bf16
// ---------------------------------------------------------------------------
__global__ __launch_bounds__(256) void prep_weights(const void* __restrict__ w,
                                                    const void* __restrict__ asc,
                                                    unsigned short* __restrict__ Bpu) {
    int isbf = detect_bf16(asc);
    int idx = blockIdx.x * 256 + threadIdx.x;
    if (idx >= 18 * 32 * 32) return;
    int t = idx >> 10;
    int r = idx & 1023;
    int n = r >> 5;
    int k = r & 31;
    int tap = t >> 1;
    int ch = t & 1;
    float v = 0.f;
    if (n < NCO)
        v = ldF(w, ((long)n * CG + ch * 32 + k) * 9 + tap, isbf);
    Bpu[idx] = f2bfbits(v);
}

// ---------------------------------------------------------------------------
// Kernel 2 (R11): LDS-staged MFMA conv + 18 out planes + aff8 + fused cos.
//
// R11 reorder: row-0's cos gather (the longest-latency segment: 2048 scattered
// float4 loads/block) is ISSUED BEFORE the plane/aff8 store phase, so those
// independent global stores execute under the gather's memory latency instead
// of serially. zref planes (och 8,9 = 0) also written here coalesced (conv
// touches every pixel), dropping 2 stores/thread + a RAW window from final.
// All FP expressions and accumulation orders unchanged -> bit-identical.
// ---------------------------------------------------------------------------
__global__ __launch_bounds__(256, 4) void conv_mfma5_kernel(const unsigned short* __restrict__ gTu,
                                                            const unsigned short* __restrict__ Bpu,
                                                            const void* __restrict__ bias,
                                                            const void* __restrict__ asc,
                                                            const float* __restrict__ fea_cl,
                                                            float* __restrict__ aff8,
                                                            float* __restrict__ cosb,
                                                            float* __restrict__ out) {
    int isbf = detect_bf16(asc);
    const int x0 = blockIdx.x * 64;
    const int y0 = blockIdx.y * 4;
    const int b  = blockIdx.z;
    const int tid = threadIdx.x;
    const int bx = blockIdx.x;

    __shared__ unsigned short shA[6 * 66 * 64];   // 50688 B union:
    float* shO = (float*)shA;                     //   [4][24][67] f32 = 25728 B
    float* S   = (float*)((char*)shA + 25728);    //   [64][65] f32   = 16640 B

    // ---- stage rows y0-1..y0+4, px x0-1..x0+64, 64 ch bf16 (50688 B) ----
#pragma unroll
    for (int it = 0; it < 13; it++) {
        int s = it * 256 + tid;
        if (s < 3168) {
            int row = s / 528;          // 528 = 66 px * 8 blocks
            int rem = s - row * 528;
            int xi = rem >> 3;
            int blk = rem & 7;
            int y = y0 - 1 + row;
            int x = x0 - 1 + xi;
            int4 v = make_int4(0, 0, 0, 0);
            if (y >= 0 && y < HH && x >= 0 && x < WW)
                v = *(const int4*)(gTu + ((((size_t)b * HH + y) * WW + x) << 6)
                                       + ((blk ^ (xi & 7)) << 3));
            *(int4*)&shA[((row * 66 + xi) << 6) + (blk << 3)] = v;
        }
    }
    __syncthreads();

    const int wid  = tid >> 6;
    const int lane = tid & 63;
    const int m = lane & 15, quad = lane >> 4;

    f32x4 acc0[4], acc1[4];
#pragma unroll
    for (int r = 0; r < 4; r++) {
        acc0[r] = (f32x4){0.f, 0.f, 0.f, 0.f};
        acc1[r] = (f32x4){0.f, 0.f, 0.f, 0.f};
    }

#pragma unroll
    for (int tap = 0; tap < 9; tap++) {
        const int dy = tap / 3, dx = tap % 3;
        const int xi = wid * 16 + m + dx;
#pragma unroll
        for (int h = 0; h < 2; h++) {
            const int t = tap * 2 + h;
            int4 b0i = *(const int4*)(Bpu + ((t * 32 + m) * 32 + quad * 8));
            int4 b1i = *(const int4*)(Bpu + ((t * 32 + 16 + m) * 32 + quad * 8));
            bf16x8 bf0 = __builtin_bit_cast(bf16x8, b0i);
            bf16x8 bf1 = __builtin_bit_cast(bf16x8, b1i);
            const int sw = (((h * 4 + quad) ^ (xi & 7)) << 3);
#pragma unroll
            for (int r = 0; r < 4; r++) {
                int row = r + dy;
                int4 ai = *(const int4*)&shA[(((row * 66 + xi) << 6)) + sw];
                bf16x8 af = __builtin_bit_cast(bf16x8, ai);
                acc0[r] = __builtin_amdgcn_mfma_f32_16x16x32_bf16(af, bf0, acc0[r], 0, 0, 0);
                acc1[r] = __builtin_amdgcn_mfma_f32_16x16x32_bf16(af, bf1, acc1[r], 0, 0, 0);
            }
        }
    }

    const int n = m;
    float bias0 = ldF(bias, n, isbf);
    float bias1 = (n < 8) ? ldF(bias, 16 + n, isbf) : 0.f;
    const int pxl = wid * 16 + quad * 4;   // local px base 0..63

    // ---- stage all 24 output channels into shO (no oa traffic) ----
    __syncthreads();                    // shA reads done; reuse as shO/S
#pragma unroll
    for (int r = 0; r < 4; r++) {
#pragma unroll
        for (int rr = 0; rr < 4; rr++) {
            int pl = pxl + rr;
            shO[(r * 24 + n) * 67 + pl] = acc0[r][rr] + bias0;
            if (n < 8) shO[(r * 24 + 16 + n) * 67 + pl] = acc1[r][rr] + bias1;
        }
    }
    __syncthreads();

    const float* feaB = fea_cl + (size_t)b * HWSZ * 8;

    // ---- cos row 0 phase1 ISSUED FIRST (longest latency); the plane/aff8
    //      stores below then overlap the gather's memory latency ----
    {
        const int pi = y0;
#pragma unroll
        for (int k = 0; k < 2; k++) {
            int s = k * 256 + tid;
            int c = s >> 6;
            int qj_l = s & 63;
            int qj = x0 + qj_l;
            float ox = shO[(2 * c) * 67 + qj_l];
            float oy = shO[(2 * c + 1) * 67 + qj_l];
            float add = (c < 4) ? (float)pi : (float)qj;
            float px = ox + add, py = oy + add;

            float x0f = floorf(px), y0f = floorf(py);
            float wx = px - x0f, wy = py - y0f;
            int xx0 = (int)x0f, yy0 = (int)y0f;
            int x0c = min(max(xx0, 0), WW - 1), x1c = min(max(xx0 + 1, 0), WW - 1);
            int y0c = min(max(yy0, 0), HH - 1), y1c = min(max(yy0 + 1, 0), HH - 1);
            float mx0 = (xx0 == x0c) ? 1.f : 0.f;
            float mx1 = (xx0 + 1 == x1c) ? 1.f : 0.f;
            float my0 = (yy0 == y0c) ? 1.f : 0.f;
            float my1 = (yy0 + 1 == y1c) ? 1.f : 0.f;
            float aw = mx0 * (1.f - wx);
            float bw = mx1 * wx;
            float tw = my0 * (1.f - wy);
            float dw = my1 * wy;

            const float* r0 = feaB + (size_t)y0c * WW * 8;
            const float* r1 = feaB + (size_t)y1c * WW * 8;
            float v00[8], v01[8], v10[8], v11[8];
            *(float4*)&v00[0] = *(const float4*)(r0 + x0c * 8);
            *(float4*)&v00[4] = *(const float4*)(r0 + x0c * 8 + 4);
            *(float4*)&v01[0] = *(const float4*)(r0 + x1c * 8);
            *(float4*)&v01[4] = *(const float4*)(r0 + x1c * 8 + 4);
            *(float4*)&v10[0] = *(const float4*)(r1 + x0c * 8);
            *(float4*)&v10[4] = *(const float4*)(r1 + x0c * 8 + 4);
            *(float4*)&v11[0] = *(const float4*)(r1 + x1c * 8);
            *(float4*)&v11[4] = *(const float4*)(r1 + x1c * 8 + 4);

            int base = qj_l * 65 + c * 8;
#pragma unroll
            for (int ch = 0; ch < 8; ch++)
                S[base + ch] = tw * (aw * v00[ch] + bw * v01[ch])
                             + dw * (aw * v10[ch] + bw * v11[ch]);
        }
    }

    // ---- 16 offset planes of `out`, coalesced: 4096 floats ----
#pragma unroll
    for (int it = 0; it < 16; it++) {
        int s = it * 256 + tid;
        int px = s & 63;
        int rest = s >> 6;
        int nn = rest & 15;
        int r = rest >> 4;
        int och = (nn < 8) ? nn : nn + 2;
        out[(((size_t)b * 18 + och) * HH + (y0 + r)) * WW + x0 + px]
            = shO[(r * 24 + nn) * 67 + px];
    }
    // ---- zref planes (och 8,9) = 0, coalesced: 512 floats ----
#pragma unroll
    for (int it = 0; it < 2; it++) {
        int s = it * 256 + tid;
        int px = s & 63;
        int r = (s >> 6) & 3;
        int p = s >> 8;
        out[(((size_t)b * 18 + 8 + p) * HH + (y0 + r)) * WW + x0 + px] = 0.f;
    }
    // ---- aff8 channels-last, coalesced: 2048 floats ----
#pragma unroll
    for (int it = 0; it < 8; it++) {
        int s = it * 256 + tid;
        int n8 = s & 7;
        int px = (s >> 3) & 63;
        int r = s >> 9;
        aff8[((((size_t)b * HH + y0 + r) * WW + x0 + px) << 3) + n8]
            = shO[(r * 24 + 16 + n8) * 67 + px];
    }

    // ---- cos rows: reduce r (S ready), then phase1 r+1 ----
#pragma unroll 1
    for (int r = 0; r < 4; r++) {
        const int pi = y0 + r;
        __syncthreads();   // S writes of row r complete

        {
            int pix = tid >> 2;     // 0..63: (g, c_img)
            int cp  = tid & 3;      // computes c = 2cp, 2cp+1
            int g = pix >> 3;
            int c_img = pix & 7;
            int i = c_img * 30 + (pi >> 3);
            int j = (pi & 7) * 40 + bx * 8 + g;
            const float* fp = feaB + ((size_t)i * WW + j) * 8;
            float f[8];
            *(float4*)&f[0] = *(const float4*)fp;
            *(float4*)&f[4] = *(const float4*)(fp + 4);
            float a0 = 0.f, a1 = 0.f;
            int c0 = 2 * cp;
#pragma unroll
            for (int nn = 0; nn < 8; nn++) {   // ascending n: same FP order
                float fn = f[nn];
                int rb = (8 * g + nn) * 65 + c_img;
                a0 += fn * S[rb + c0 * 8];
                a1 += fn * S[rb + (c0 + 1) * 8];
            }
            float* dst = cosb + (((size_t)b * HH + i) * WW + j) * 8 + c0;
            *(float2*)dst = make_float2(a0, a1);
        }

        if (r == 3) break;
        __syncthreads();   // S reads of row r complete; refill for r+1

        {
            const int pi2 = y0 + r + 1;
#pragma unroll
            for (int k = 0; k < 2; k++) {
                int s = k * 256 + tid;
                int c = s >> 6;
                int qj_l = s & 63;
                int qj = x0 + qj_l;
                float ox = shO[((r + 1) * 24 + 2 * c) * 67 + qj_l];
                float oy = shO[((r + 1) * 24 + 2 * c + 1) * 67 + qj_l];
                float add = (c < 4) ? (float)pi2 : (float)qj;
                float px = ox + add, py = oy + add;

                float x0f = floorf(px), y0f = floorf(py);
                float wx = px - x0f, wy = py - y0f;
                int xx0 = (int)x0f, yy0 = (int)y0f;
                int x0c = min(max(xx0, 0), WW - 1), x1c = min(max(xx0 + 1, 0), WW - 1);
                int y0c = min(max(yy0, 0), HH - 1), y1c = min(max(yy0 + 1, 0), HH - 1);
                float mx0 = (xx0 == x0c) ? 1.f : 0.f;
                float mx1 = (xx0 + 1 == x1c) ? 1.f : 0.f;
                float my0 = (yy0 == y0c) ? 1.f : 0.f;
                float my1 = (yy0 + 1 == y1c) ? 1.f : 0.f;
                float aw = mx0 * (1.f - wx);
                float bw = mx1 * wx;
                float tw = my0 * (1.f - wy);
                float dw = my1 * wy;

                const float* r0 = feaB + (size_t)y0c * WW * 8;
                const float* r1 = feaB + (size_t)y1c * WW * 8;
                float v00[8], v01[8], v10[8], v11[8];
                *(float4*)&v00[0] = *(const float4*)(r0 + x0c * 8);
                *(float4*)&v00[4] = *(const float4*)(r0 + x0c * 8 + 4);
                *(float4*)&v01[0] = *(const float4*)(r0 + x1c * 8);
                *(float4*)&v01[4] = *(const float4*)(r0 + x1c * 8 + 4);
                *(float4*)&v10[0] = *(const float4*)(r1 + x0c * 8);
                *(float4*)&v10[4] = *(const float4*)(r1 + x0c * 8 + 4);
                *(float4*)&v11[0] = *(const float4*)(r1 + x1c * 8);
                *(float4*)&v11[4] = *(const float4*)(r1 + x1c * 8 + 4);

                int base = qj_l * 65 + c * 8;
#pragma unroll
                for (int ch = 0; ch < 8; ch++)
                    S[base + ch] = tw * (aw * v00[ch] + bw * v01[ch])
                                 + dw * (aw * v10[ch] + bw * v11[ch]);
            }
        }
    }
}

// ---------------------------------------------------------------------------
// Fallback scalar conv (only if ws too small for gTu).
// ---------------------------------------------------------------------------
__global__ __launch_bounds__(256, 4) void conv_fallback(const void* __restrict__ g,
                                                        const void* __restrict__ w,
                                                        const void* __restrict__ bias,
                                                        const void* __restrict__ asc,
                                                        float* __restrict__ oa) {
    int isbf = detect_bf16(asc);
    const int b = blockIdx.z;
    const int i0 = blockIdx.y * 16;
    const int j0 = blockIdx.x * 16;
    const int tx = threadIdx.x & 15;
    const int ty = threadIdx.x >> 4;

    __shared__ float gl[8][18][20];
    __shared__ float wl[8][NCO][10];

    float acc[NCO];
#pragma unroll
    for (int c = 0; c < NCO; c++) acc[c] = ldF(bias, c, isbf);

    for (int ci0 = 0; ci0 < CG; ci0 += 8) {
        __syncthreads();
        for (int idx = threadIdx.x; idx < 8 * NCO * 9; idx += 256) {
            int t = idx % 9;
            int rest = idx / 9;
            int cc = rest & 7;
            int co = rest >> 3;
            wl[cc][co][t] = ldF(w, (long)(co * CG + ci0 + cc) * 9 + t, isbf);
        }
        for (int idx = threadIdx.x; idx < 8 * 18 * 18; idx += 256) {
            int cc = idx / 324;
            int rem = idx - cc * 324;
            int r = rem / 18;
            int c2 = rem - r * 18;
            int gi = i0 - 1 + r;
            int gj = j0 - 1 + c2;
            float v = 0.f;
            if (gi >= 0 && gi < HH && gj >= 0 && gj < WW)
                v = ldF(g, ((long)(b * CG + ci0 + cc) * HH + gi) * WW + gj, isbf);
            gl[cc][r][c2] = v;
        }
        __syncthreads();
#pragma unroll
        for (int cc = 0; cc < 8; cc++) {
            float ga[9];
#pragma unroll
            for (int dy = 0; dy < 3; dy++)
#pragma unroll
                for (int dx = 0; dx < 3; dx++)
                    ga[dy * 3 + dx] = gl[cc][ty + dy][tx + dx];
#pragma unroll 4
            for (int co = 0; co < NCO; co++) {
                float s = 0.f;
#pragma unroll
                for (int t = 0; t < 9; t++)
                    s += wl[cc][co][t] * ga[t];
                acc[co] += s;
            }
        }
    }
    int i = i0 + ty, j = j0 + tx;
    float4* p = (float4*)&oa[(((size_t)b * HH + i) * WW + j) * NCO];
#pragma unroll
    for (int q = 0; q < 6; q++)
        p[q] = make_float4(acc[4 * q], acc[4 * q + 1], acc[4 * q + 2], acc[4 * q + 3]);
}

// ---------------------------------------------------------------------------
// Branchless bilinear, zero outside: clamp indices, mask corner weights.
// ---------------------------------------------------------------------------
__device__ __forceinline__ float bil_zero_f32(const float* __restrict__ img,
                                              float x, float y) {
    float x0f = floorf(x), y0f = floorf(y);
    float wx = x - x0f, wy = y - y0f;
    int x0 = (int)x0f, y0 = (int)y0f;
    int x0c = min(max(x0, 0), WW - 1), x1c = min(max(x0 + 1, 0), WW - 1);
    int y0c = min(max(y0, 0), HH - 1), y1c = min(max(y0 + 1, 0), HH - 1);
    float mx0 = (x0 == x0c) ? 1.f : 0.f;
    float mx1 = (x0 + 1 == x1c) ? 1.f : 0.f;
    float my0 = (y0 == y0c) ? 1.f : 0.f;
    float my1 = (y0 + 1 == y1c) ? 1.f : 0.f;
    const float* r0 = img + (size_t)y0c * WW;
    const float* r1 = img + (size_t)y1c * WW;
    float v00 = r0[x0c], v01 = r0[x1c], v10 = r1[x0c], v11 = r1[x1c];
    return my0 * (1.f - wy) * (mx0 * (1.f - wx) * v00 + mx1 * wx * v01)
         + my1 * wy * (mx0 * (1.f - wx) * v10 + mx1 * wx * v11);
}

__device__ __forceinline__ float bil_zero_poly(const void* __restrict__ img, long base,
                                               float x, float y, int isbf) {
    float x0f = floorf(x), y0f = floorf(y);
    float wx = x - x0f, wy = y - y0f;
    int x0 = (int)x0f, y0 = (int)y0f;
    int x0c = min(max(x0, 0), WW - 1), x1c = min(max(x0 + 1, 0), WW - 1);
    int y0c = min(max(y0, 0), HH - 1), y1c = min(max(y0 + 1, 0), HH - 1);
    float mx0 = (x0 == x0c) ? 1.f : 0.f;
    float mx1 = (x0 + 1 == x1c) ? 1.f : 0.f;
    float my0 = (y0 == y0c) ? 1.f : 0.f;
    float my1 = (y0 + 1 == y1c) ? 1.f : 0.f;
    long r0 = base + (long)y0c * WW;
    long r1 = base + (long)y1c * WW;
    float v00 = ldF(img, r0 + x0c, isbf), v01 = ldF(img, r0 + x1c, isbf);
    float v10 = ldF(img, r1 + x0c, isbf), v11 = ldF(img, r1 + x1c, isbf);
    return my0 * (1.f - wy) * (mx0 * (1.f - wx) * v00 + mx1 * wx * v01)
         + my1 * wy * (mx0 * (1.f - wx) * v10 + mx1 * wx * v11);
}

// ---------------------------------------------------------------------------
// Kernel 3a (mid path only): source-centric cosine affinity.
// ---------------------------------------------------------------------------
__global__ __launch_bounds__(256, 4) void cos_kernel(const float* __restrict__ oa,
                                                     const float* __restrict__ fea_cl,
                                                     float* __restrict__ cos_buf) {
    __shared__ float S_lds[64 * 65];
    const int bx = blockIdx.x;   // 0..4 (qj chunk of 64)
    const int pi = blockIdx.y;   // 0..239
    const int b  = blockIdx.z;
    const int tid = threadIdx.x;
    const int qj_l = tid & 63;
    const int cpair = tid >> 6;  // 0..3 -> c in {2cp, 2cp+1}
    const int qj = bx * 64 + qj_l;

    const float* feaB = fea_cl + (size_t)b * HWSZ * 8;
    const float4 ov = *(const float4*)&oa[(((size_t)b * HH + pi) * WW + qj) * NCO + 4 * cpair];

#pragma unroll
    for (int t = 0; t < 2; t++) {
        int c = 2 * cpair + t;
        float ox = (t == 0) ? ov.x : ov.z;
        float oy = (t == 0) ? ov.y : ov.w;
        float add = (c < 4) ? (float)pi : (float)qj;   // wave-uniform branch
        float px = ox + add, py = oy + add;

        float x0f = floorf(px), y0f = floorf(py);
        float wx = px - x0f, wy = py - y0f;
        int x0 = (int)x0f, y0 = (int)y0f;
        int x0c = min(max(x0, 0), WW - 1), x1c = min(max(x0 + 1, 0), WW - 1);
        int y0c = min(max(y0, 0), HH - 1), y1c = min(max(y0 + 1, 0), HH - 1);
        float mx0 = (x0 == x0c) ? 1.f : 0.f;
        float mx1 = (x0 + 1 == x1c) ? 1.f : 0.f;
        float my0 = (y0 == y0c) ? 1.f : 0.f;
        float my1 = (y0 + 1 == y1c) ? 1.f : 0.f;
        float aw = mx0 * (1.f - wx);
        float bw = mx1 * wx;
        float tw = my0 * (1.f - wy);
        float dw = my1 * wy;

        const float* r0 = feaB + (size_t)y0c * WW * 8;
        const float* r1 = feaB + (size_t)y1c * WW * 8;
        float v00[8], v01[8], v10[8], v11[8];
        *(float4*)&v00[0] = *(const float4*)(r0 + x0c * 8);
        *(float4*)&v00[4] = *(const float4*)(r0 + x0c * 8 + 4);
        *(float4*)&v01[0] = *(const float4*)(r0 + x1c * 8);
        *(float4*)&v01[4] = *(const float4*)(r0 + x1c * 8 + 4);
        *(float4*)&v10[0] = *(const float4*)(r1 + x0c * 8);
        *(float4*)&v10[4] = *(const float4*)(r1 + x0c * 8 + 4);
        *(float4*)&v11[0] = *(const float4*)(r1 + x1c * 8);
        *(float4*)&v11[4] = *(const float4*)(r1 + x1c * 8 + 4);

        int base = qj_l * 65 + c * 8;
#pragma unroll
        for (int ch = 0; ch < 8; ch++)
            S_lds[base + ch] = tw * (aw * v00[ch] + bw * v01[ch])
                             + dw * (aw * v10[ch] + bw * v11[ch]);
    }

    __syncthreads();

    {
        int pix = tid >> 2;     // 0..63: (g, c_img)
        int cp  = tid & 3;      // computes c = 2cp, 2cp+1
        int g = pix >> 3;
        int c_img = pix & 7;
        int i = c_img * 30 + (pi >> 3);
        int j = (pi & 7) * 40 + bx * 8 + g;
        const float* fp = feaB + ((size_t)i * WW + j) * 8;
        float f[8];
        *(float4*)&f[0] = *(const float4*)fp;
        *(float4*)&f[4] = *(const float4*)(fp + 4);
        float a0 = 0.f, a1 = 0.f;
        int c0 = 2 * cp;
#pragma unroll
        for (int n = 0; n < 8; n++) {       // ascending n: same FP order
            float fn = f[n];
            int rb = (8 * g + n) * 65 + c_img;
            a0 += fn * S_lds[rb + c0 * 8];
            a1 += fn * S_lds[rb + (c0 + 1) * 8];
        }
        float* dst = cos_buf + (((size_t)b * HH + i) * WW + j) * 8 + c0;
        *(float2*)dst = make_float2(a0, a1);
    }
}

// ---------------------------------------------------------------------------
// Kernel 3b (R11, full path): epilogue reading offsets from out planes +
// aff logits from aff8. zref planes written by conv. Fast tanh.
// ---------------------------------------------------------------------------
__global__ __launch_bounds__(256, 4) void final4_kernel(const float* __restrict__ aff8,
                                                        const float* __restrict__ cos_buf,
                                                        const void* __restrict__ conf_in,
                                                        const void* __restrict__ asc_p,
                                                        float* __restrict__ out) {
    int isbf = detect_bf16(asc_p);
    int idx = blockIdx.x * 256 + threadIdx.x;
    if (idx >= BB * HWSZ) return;
    int j = idx % WW;
    int rest = idx / WW;
    int i = rest % HH;
    int b = rest / HH;

    float cos_acc[8];
    {
        const float* cp = cos_buf + (size_t)idx * 8;
        float4 ca = *(const float4*)cp;
        float4 cb = *(const float4*)(cp + 4);
        cos_acc[0] = ca.x; cos_acc[1] = ca.y; cos_acc[2] = ca.z; cos_acc[3] = ca.w;
        cos_acc[4] = cb.x; cos_acc[5] = cb.y; cos_acc[6] = cb.z; cos_acc[7] = cb.w;
    }
    float affl[8];
    {
        const float* ap = aff8 + (size_t)idx * 8;
        float4 aa = *(const float4*)ap;
        float4 ab = *(const float4*)(ap + 4);
        affl[0] = aa.x; affl[1] = aa.y; affl[2] = aa.z; affl[3] = aa.w;
        affl[4] = ab.x; affl[5] = ab.y; affl[6] = ab.z; affl[7] = ab.w;
    }
    // offsets ch0..15 from the 16 out planes (coalesced; L2-warm, just written)
    size_t pix = (size_t)i * WW + j;
    float offs[16];
#pragma unroll
    for (int ch = 0; ch < 16; ch++) {
        int och = (ch < 8) ? ch : ch + 2;
        offs[ch] = out[((size_t)b * 18 + och) * HWSZ + pix];
    }

    float asc = ldF(asc_p, 0, isbf) + 1e-8f;
    long cbase = (long)b * HWSZ;

    float a[8];
    float ssum = 0.f;
#pragma unroll
    for (int c = 0; c < 8; c++) {
        float v = affl[c] * cos_acc[c];
        float e2 = __expf(2.f * v);
        v = (1.f - 2.f / (e2 + 1.f)) / asc;
        float py2 = offs[2 * c] + (float)i;
        float px2 = offs[2 * c + 1] + (float)j;
        float cf = bil_zero_poly(conf_in, cbase, px2, py2, isbf);
        v *= cf;
        a[c] = v;
        ssum += fabsf(v);
    }
    ssum += 1e-4f;
    ssum = fmaxf(ssum, 1.0f);
    float inv = 1.0f / ssum;
    float asum = 0.f;
#pragma unroll
    for (int c = 0; c < 8; c++) { a[c] *= inv; asum += a[c]; }
    float aref = 1.0f - asum;

    float vals[9];
#pragma unroll
    for (int c = 0; c < 4; c++) vals[c] = a[c];
    vals[4] = aref;
#pragma unroll
    for (int c = 4; c < 8; c++) vals[c + 1] = a[c];
    float m = vals[0];
#pragma unroll
    for (int k = 1; k < 9; k++) m = fmaxf(m, vals[k]);
    float es = 0.f;
#pragma unroll
    for (int k = 0; k < 9; k++) { vals[k] = __expf(vals[k] - m); es += vals[k]; }
    float ei = 1.0f / es;

    float* aff_out = out + (size_t)BB * 18 * HWSZ;
    size_t base_a = (size_t)b * 9 * HWSZ + pix;
#pragma unroll
    for (int k = 0; k < 9; k++)
        aff_out[base_a + (size_t)k * HWSZ] = vals[k] * ei;
}

// ---------------------------------------------------------------------------
// Kernel 3b (mid path): full epilogue incl. all 18 offset planes (uses oa).
// ---------------------------------------------------------------------------
__global__ __launch_bounds__(256, 4) void final2_kernel(const float* __restrict__ oa,
                                                        const float* __restrict__ cos_buf,
                                                        const void* __restrict__ conf_in,
                                                        const void* __restrict__ asc_p,
                                                        float* __restrict__ out) {
    int isbf = detect_bf16(asc_p);
    int idx = blockIdx.x * 256 + threadIdx.x;
    if (idx >= BB * HWSZ) return;
    int j = idx % WW;
    int rest = idx / WW;
    int i = rest % HH;
    int b = rest / HH;

    float cos_acc[8];
    {
        const float* cp = cos_buf + (size_t)idx * 8;
        float4 ca = *(const float4*)cp;
        float4 cb = *(const float4*)(cp + 4);
        cos_acc[0] = ca.x; cos_acc[1] = ca.y; cos_acc[2] = ca.z; cos_acc[3] = ca.w;
        cos_acc[4] = cb.x; cos_acc[5] = cb.y; cos_acc[6] = cb.z; cos_acc[7] = cb.w;
    }

    const float4* op = (const float4*)&oa[(((size_t)b * HH + i) * WW + j) * NCO];
    float own[24];
#pragma unroll
    for (int q = 0; q < 6; q++) {
        float4 v = op[q];
        own[4 * q] = v.x; own[4 * q + 1] = v.y; own[4 * q + 2] = v.z; own[4 * q + 3] = v.w;
    }

    float asc = ldF(asc_p, 0, isbf) + 1e-8f;
    long cbase = (long)b * HWSZ;

    float a[8];
    float ssum = 0.f;
#pragma unroll
    for (int c = 0; c < 8; c++) {
        float v = own[16 + c] * cos_acc[c];
        v = tanhf(v) / asc;
        float py2 = own[2 * c] + (float)i;
        float px2 = own[2 * c + 1] + (float)j;
        float cf = bil_zero_poly(conf_in, cbase, px2, py2, isbf);
        v *= cf;
        a[c] = v;
        ssum += fabsf(v);
    }
    ssum += 1e-4f;
    ssum = fmaxf(ssum, 1.0f);
    float inv = 1.0f / ssum;
    float asum = 0.f;
#pragma unroll
    for (int c = 0; c < 8; c++) { a[c] *= inv; asum += a[c]; }
    float aref = 1.0f - asum;

    float vals[9];
#pragma unroll
    for (int c = 0; c < 4; c++) vals[c] = a[c];
    vals[4] = aref;
#pragma unroll
    for (int c = 4; c < 8; c++) vals[c + 1] = a[c];
    float m = vals[0];
#pragma unroll
    for (int k = 1; k < 9; k++) m = fmaxf(m, vals[k]);
    float es = 0.f;
#pragma unroll
    for (int k = 0; k < 9; k++) { vals[k] = __expf(vals[k] - m); es += vals[k]; }
    float ei = 1.0f / es;

    size_t pix = (size_t)i * WW + j;
    size_t base_o = (size_t)b * 18 * HWSZ + pix;
#pragma unroll
    for (int ch = 0; ch < 18; ch++) {
        float v;
        if (ch < 8) v = own[ch];
        else if (ch < 10) v = 0.f;
        else v = own[ch - 2];
        out[base_o + (size_t)ch * HWSZ] = v;
    }
    float* aff_out = out + (size_t)BB * 18 * HWSZ;
    size_t base_a = (size_t)b * 9 * HWSZ + pix;
#pragma unroll
    for (int k = 0; k < 9; k++)
        aff_out[base_a + (size_t)k * HWSZ] = vals[k] * ei;
}

// ---------------------------------------------------------------------------
// OLD monolithic final kernel — emergency fallback only (tiny workspace).
// ---------------------------------------------------------------------------
__global__ __launch_bounds__(256, 4) void final_kernel(const float* __restrict__ oa,
                                                       const float* __restrict__ fea,
                                                       const void* __restrict__ conf_in,
                                                       const void* __restrict__ asc_p,
                                                       float* __restrict__ out) {
    int isbf = detect_bf16(asc_p);
    int idx = blockIdx.x * 256 + threadIdx.x;
    if (idx >= BB * HWSZ) return;
    int j = idx % WW;
    int rest = idx / WW;
    int i = rest % HH;
    int b = rest / HH;

    const float* feaB = fea + (size_t)b * 8 * HWSZ;
    float f[8];
#pragma unroll
    for (int n = 0; n < 8; n++)
        f[n] = feaB[(size_t)n * HWSZ + (size_t)i * WW + j];

    int c_img = i / 30;
    int pi = (i % 30) * 8 + j / 40;
    int pj0 = (j % 40) * 8;
    const float* feaC = feaB + (size_t)c_img * HWSZ;

    float cos_acc[8];
#pragma unroll
    for (int c = 0; c < 8; c++) cos_acc[c] = 0.f;

#pragma unroll 1
    for (int n = 0; n < 8; n++) {
        int qj = pj0 + n;
        const float4* oq = (const float4*)&oa[(((size_t)b * HH + pi) * WW + qj) * NCO];
        float4 o0 = oq[0], o1 = oq[1], o2 = oq[2], o3 = oq[3];
        float off[16] = {o0.x, o0.y, o0.z, o0.w, o1.x, o1.y, o1.z, o1.w,
                         o2.x, o2.y, o2.z, o2.w, o3.x, o3.y, o3.z, o3.w};
        float fn = f[n];
#pragma unroll
        for (int c = 0; c < 8; c++) {
            float add = (c < 4) ? (float)pi : (float)qj;
            float px = off[2 * c] + add;
            float py = off[2 * c + 1] + add;
            cos_acc[c] += fn * bil_zero_f32(feaC, px, py);
        }
    }

    const float4* op = (const float4*)&oa[(((size_t)b * HH + i) * WW + j) * NCO];
    float own[24];
#pragma unroll
    for (int q = 0; q < 6; q++) {
        float4 v = op[q];
        own[4 * q] = v.x; own[4 * q + 1] = v.y; own[4 * q + 2] = v.z; own[4 * q + 3] = v.w;
    }

    float asc = ldF(asc_p, 0, isbf) + 1e-8f;
    long cbase = (long)b * HWSZ;

    float a[8];
    float ssum = 0.f;
#pragma unroll
    for (int c = 0; c < 8; c++) {
        float v = own[16 + c] * cos_acc[c];
        v = tanhf(v) / asc;
        float py2 = own[2 * c] + (float)i;
        float px2 = own[2 * c + 1] + (float)j;
        float cf = bil_zero_poly(conf_in, cbase, px2, py2, isbf);
        v *= cf;
        a[c] = v;
        ssum += fabsf(v);
    }
    ssum += 1e-4f;
    ssum = fmaxf(ssum, 1.0f);
    float inv = 1.0f / ssum;
    float asum = 0.f;
#pragma unroll
    for (int c = 0; c < 8; c++) { a[c] *= inv; asum += a[c]; }
    float aref = 1.0f - asum;

    float vals[9];
#pragma unroll
    for (int c = 0; c < 4; c++) vals[c] = a[c];
    vals[4] = aref;
#pragma unroll
    for (int c = 4; c < 8; c++) vals[c + 1] = a[c];
    float m = vals[0];
#pragma unroll
    for (int k = 1; k < 9; k++) m = fmaxf(m, vals[k]);
    float es = 0.f;
#pragma unroll
    for (int k = 0; k < 9; k++) { vals[k] = __expf(vals[k] - m); es += vals[k]; }
    float ei = 1.0f / es;

    size_t pix = (size_t)i * WW + j;
    size_t base_o = (size_t)b * 18 * HWSZ + pix;
#pragma unroll
    for (int ch = 0; ch < 18; ch++) {
        float v;
        if (ch < 8) v = own[ch];
        else if (ch < 10) v = 0.f;
        else v = own[ch - 2];
        out[base_o + (size_t)ch * HWSZ] = v;
    }
    float* aff_out = out + (size_t)BB * 18 * HWSZ;
    size_t base_a = (size_t)b * 9 * HWSZ + pix;
#pragma unroll
    for (int k = 0; k < 9; k++)
        aff_out[base_a + (size_t)k * HWSZ] = vals[k] * ei;
}

// ---------------------------------------------------------------------------
extern "C" void kernel_launch(void* const* d_in, const int* in_sizes, int n_in,
                              void* d_out, int out_size, void* d_ws, size_t ws_size,
                              hipStream_t stream) {
    const void* guidance = d_in[0];
    const void* gtconf   = d_in[1];
    const void* tgt      = d_in[2];
    const void* conv_w   = d_in[3];
    const void* conv_b   = d_in[4];
    const void* asc      = d_in[5];

    // Workspace layout (full path no longer uses oa; its region hosts aff8):
    //   oa/aff8 : 29,491,200 B (aff8 uses first 9.8 MB in full path)
    //   fea     :  9,830,400 B
    //   cosb    :  9,830,400 B
    //   big     : 39,321,600 B (tcl | gTu time-shared)
    //   Bpu     :     36,864 B
    float* oa   = (float*)d_ws;
    float* aff8 = oa;                       // full path alias (oa unused there)
    float* fea  = oa + (size_t)BB * HWSZ * NCO;
    float* cosb = fea + (size_t)BB * 8 * HWSZ;
    float* big  = cosb + (size_t)BB * 8 * HWSZ;
    unsigned short* gTu = (unsigned short*)big;
    float* tcl  = big;
    unsigned short* Bpu = (unsigned short*)((char*)big + (size_t)39321600);
    const size_t ws_full = (size_t)29491200 + 9830400 + 9830400 + 39321600 + 36864; // 88,510,464
    const size_t ws_mid  = (size_t)29491200 + 9830400 + 9830400;                    // 49,152,000
    float* out = (float*)d_out;

    int n_pix = BB * HWSZ;
    int n_tgt = BB * 8 * 120 * 160;

    if (ws_size >= ws_full) {
        tgt_cl_kernel<<<(n_tgt + 255) / 256, 256, 0, stream>>>(tgt, asc, tcl);
        upsample_cl2_kernel<<<(n_pix + 255) / 256, 256, 0, stream>>>(tcl, fea);
        prep_weights<<<72, 256, 0, stream>>>(conv_w, asc, Bpu);
        dim3 pgrid(WW / 64, HH, BB);
        prep_guidance2<<<pgrid, 256, 0, stream>>>(guidance, asc, gTu);
        dim3 cgrid(WW / 64, HH / 4, BB);
        conv_mfma5_kernel<<<cgrid, 256, 0, stream>>>(gTu, Bpu, conv_b, asc, fea,
                                                     aff8, cosb, out);
        final4_kernel<<<(n_pix + 255) / 256, 256, 0, stream>>>(aff8, cosb, gtconf, asc, out);
    } else if (ws_size >= ws_mid) {
        // mid path: no gTu; scalar conv + split cos/final2 (uses oa). tcl
        // aliases cosb (disjoint liveness).
        float* tclm = cosb;
        tgt_cl_kernel<<<(n_tgt + 255) / 256, 256, 0, stream>>>(tgt, asc, tclm);
        upsample_cl2_kernel<<<(n_pix + 255) / 256, 256, 0, stream>>>(tclm, fea);
        dim3 cgrid(WW / 16, HH / 16, BB);
        conv_fallback<<<cgrid, 256, 0, stream>>>(guidance, conv_w, conv_b, asc, oa);
        dim3 ggrid(WW / 64, HH, BB);
        cos_kernel<<<ggrid, 256, 0, stream>>>(oa, fea, cosb);
        final2_kernel<<<(n_pix + 255) / 256, 256, 0, stream>>>(oa, cosb, gtconf, asc, out);
    } else {
        // --- emergency tiny-workspace path (old monolithic) ---
        int n_up = BB * 8 * HWSZ;
        upsample_kernel<<<(n_up + 255) / 256, 256, 0, stream>>>(tgt, asc, fea);
        dim3 cgrid(WW / 16, HH / 16, BB);
        conv_fallback<<<cgrid, 256, 0, stream>>>(guidance, conv_w, conv_b, asc, oa);
        final_kernel<<<(n_pix + 255) / 256, 256, 0, stream>>>(oa, fea, gtconf, asc, out);
    }
}